// Round 8
// baseline (864.181 us; speedup 1.0000x reference)
//
#include <hip/hip_runtime.h>
#include <math.h>

// ---------------------------------------------------------------------------
// MLPEncoder (NRI encoder) on MI355X — round 8: kill the hot-atomic wall.
//   R7 structure kept. edge_mlp4's BN-stats epilogue no longer does 4950
//   serialized atomicAdds per channel; it writes per-block bf16 partials
//   (coalesced) and a 64-block reduce_stats kernel finishes the reduction.
//   final_kernel: uint4 (16B/lane) row reads.
// ---------------------------------------------------------------------------

typedef unsigned short ushort_t;
typedef __bf16 bf16x8 __attribute__((ext_vector_type(8)));
typedef float  f32x4  __attribute__((ext_vector_type(4)));

#define E_EDGES 9900
#define NNODE   100
#define HID     256
#define M_BIG   316800
#define M_SMALL 3200
#define NBLK    (M_BIG / 64)   /* 4950 */

__device__ __forceinline__ float bf2f(ushort_t u) {
    union { unsigned int i; float f; } v; v.i = ((unsigned int)u) << 16; return v.f;
}
__device__ __forceinline__ ushort_t f2bf(float f) {
    union { float f; unsigned int i; } v; v.f = f;
    return (ushort_t)((v.i + 0x7fffu + ((v.i >> 16) & 1u)) >> 16);   // RNE
}
__device__ __forceinline__ float elu_f(float x) {
    return x > 0.f ? x : (__expf(x) - 1.f);
}

// ---- convert+transpose 3 [256,256] fp32 matrices -> bf16 WT[chan][256] ----
__global__ __launch_bounds__(256)
void wcvt3_kernel(const float* __restrict__ W0, const float* __restrict__ W1,
                  const float* __restrict__ W2,
                  ushort_t* __restrict__ T0, ushort_t* __restrict__ T1,
                  ushort_t* __restrict__ T2)
{
    int bid = blockIdx.x;
    const float* W; ushort_t* WT; int tile;
    if (bid < 16)      { W = W0; WT = T0; tile = bid; }
    else if (bid < 32) { W = W1; WT = T1; tile = bid - 16; }
    else               { W = W2; WT = T2; tile = bid - 32; }
    int k0 = (tile >> 2) * 64, c0 = (tile & 3) * 64;
    __shared__ float S[64][65];
    int t = threadIdx.x;
    #pragma unroll
    for (int i = 0; i < 16; ++i) {
        int idx = t + i * 256;
        S[idx >> 6][idx & 63] = W[(size_t)(k0 + (idx >> 6)) * 256 + c0 + (idx & 63)];
    }
    __syncthreads();
    int col = t & 63;
    int kb  = (t >> 6) * 16;
    ushort_t* dst = WT + (size_t)(c0 + col) * 256 + k0 + kb;
    #pragma unroll
    for (int jj = 0; jj < 4; ++jj) {
        ushort4 u;
        u.x = f2bf(S[kb + 4 * jj + 0][col]);
        u.y = f2bf(S[kb + 4 * jj + 1][col]);
        u.z = f2bf(S[kb + 4 * jj + 2][col]);
        u.w = f2bf(S[kb + 4 * jj + 3][col]);
        *(ushort4*)(dst + 4 * jj) = u;
    }
}

// ---- fused small 2-layer fp32 MLP: X[3200,K0] -> ELU MLP -> fp32 [3200,256]
#define FMA_ROW(ri, xs) \
    acc[ri][0] = fmaf(xs, w.x, acc[ri][0]); \
    acc[ri][1] = fmaf(xs, w.y, acc[ri][1]); \
    acc[ri][2] = fmaf(xs, w.z, acc[ri][2]); \
    acc[ri][3] = fmaf(xs, w.w, acc[ri][3]);

__global__ __launch_bounds__(256, 2)
void fused_small(const float* __restrict__ X, int K0, float xscale,
                 const float* __restrict__ W1, const float* __restrict__ b1,
                 const float* __restrict__ W2, const float* __restrict__ b2,
                 float* __restrict__ Yf)
{
    __shared__ float Xs[32][68];
    __shared__ float Ws[32][256];
    __shared__ float Hs[64][257];
    const int tid = threadIdx.x;
    const int Rbase = blockIdx.x * 64;
    const int c0 = (tid & 63) * 4;
    const int r0 = (tid >> 6) * 16;
    const int r_st = tid & 63;
    const int kb = (tid >> 6) * 8;

    float acc[16][4];
    #pragma unroll
    for (int i = 0; i < 16; ++i)
        #pragma unroll
        for (int j = 0; j < 4; ++j) acc[i][j] = 0.f;

    const int nch = (K0 + 31) >> 5;
    for (int kc = 0; kc < nch; ++kc) {
        if (kc) __syncthreads();
        {
            int kg = kc * 32 + kb;
            const float* p = X + (size_t)(Rbase + r_st) * K0 + kg;
            float v[8];
            if (kg + 8 <= K0) {
                float4 a = *(const float4*)p;
                float4 b = *(const float4*)(p + 4);
                v[0]=a.x; v[1]=a.y; v[2]=a.z; v[3]=a.w;
                v[4]=b.x; v[5]=b.y; v[6]=b.z; v[7]=b.w;
            } else {
                #pragma unroll
                for (int j = 0; j < 8; ++j) v[j] = (kg + j < K0) ? p[j] : 0.f;
            }
            #pragma unroll
            for (int j = 0; j < 8; ++j) Xs[kb + j][r_st] = v[j];
        }
        #pragma unroll
        for (int m = 0; m < 8; ++m) {
            int f  = tid + m * 256;
            int kk = f >> 6;
            int cc = (f & 63) * 4;
            int kg = kc * 32 + kk;
            float4 w = (kg < K0) ? *(const float4*)&W1[(size_t)kg * 256 + cc]
                                 : make_float4(0.f, 0.f, 0.f, 0.f);
            *(float4*)&Ws[kk][cc] = w;
        }
        __syncthreads();
        #pragma unroll 8
        for (int kk = 0; kk < 32; ++kk) {
            float4 w = *(const float4*)&Ws[kk][c0];
            #pragma unroll
            for (int i = 0; i < 4; ++i) {
                float4 x = *(const float4*)&Xs[kk][r0 + 4 * i];
                FMA_ROW(4 * i + 0, x.x)
                FMA_ROW(4 * i + 1, x.y)
                FMA_ROW(4 * i + 2, x.z)
                FMA_ROW(4 * i + 3, x.w)
            }
        }
    }
    {
        float4 bv = *(const float4*)&b1[c0];
        #pragma unroll
        for (int i = 0; i < 16; ++i) {
            Hs[r0 + i][c0 + 0] = elu_f(acc[i][0] * xscale + bv.x);
            Hs[r0 + i][c0 + 1] = elu_f(acc[i][1] * xscale + bv.y);
            Hs[r0 + i][c0 + 2] = elu_f(acc[i][2] * xscale + bv.z);
            Hs[r0 + i][c0 + 3] = elu_f(acc[i][3] * xscale + bv.w);
        }
    }
    #pragma unroll
    for (int i = 0; i < 16; ++i)
        #pragma unroll
        for (int j = 0; j < 4; ++j) acc[i][j] = 0.f;
    for (int kc = 0; kc < 8; ++kc) {
        __syncthreads();
        {
            #pragma unroll
            for (int j = 0; j < 8; ++j) Xs[kb + j][r_st] = Hs[r_st][kc * 32 + kb + j];
        }
        #pragma unroll
        for (int m = 0; m < 8; ++m) {
            int f  = tid + m * 256;
            int kk = f >> 6;
            int cc = (f & 63) * 4;
            *(float4*)&Ws[kk][cc] = *(const float4*)&W2[(size_t)(kc * 32 + kk) * 256 + cc];
        }
        __syncthreads();
        #pragma unroll 8
        for (int kk = 0; kk < 32; ++kk) {
            float4 w = *(const float4*)&Ws[kk][c0];
            #pragma unroll
            for (int i = 0; i < 4; ++i) {
                float4 x = *(const float4*)&Xs[kk][r0 + 4 * i];
                FMA_ROW(4 * i + 0, x.x)
                FMA_ROW(4 * i + 1, x.y)
                FMA_ROW(4 * i + 2, x.z)
                FMA_ROW(4 * i + 3, x.w)
            }
        }
    }
    {
        float4 bv = *(const float4*)&b2[c0];
        #pragma unroll
        for (int i = 0; i < 16; ++i) {
            int R = Rbase + r0 + i;
            *(float4*)&Yf[(size_t)R * 256 + c0] = make_float4(
                elu_f(acc[i][0] + bv.x), elu_f(acc[i][1] + bv.y),
                elu_f(acc[i][2] + bv.z), elu_f(acc[i][3] + bv.w));
        }
    }
}

// ---- P/Q partial GEMMs: P = X@Wa + biasA (no act), Q = X@Wb (bf16 out) ----
__global__ __launch_bounds__(256, 2)
void pq_gemm(const float* __restrict__ X,
             const float* __restrict__ Wa, const float* __restrict__ Wb_,
             const float* __restrict__ biasA,
             ushort_t* __restrict__ Yp, ushort_t* __restrict__ Yq)
{
    const int bid = blockIdx.x;
    const float* W; const float* bias; ushort_t* Y; int Rbase;
    if (bid < 50) { W = Wa;  bias = biasA;  Y = Yp; Rbase = bid * 64; }
    else          { W = Wb_; bias = nullptr; Y = Yq; Rbase = (bid - 50) * 64; }

    __shared__ float Xs[32][68];
    __shared__ float Ws[32][256];
    const int tid = threadIdx.x;
    const int c0 = (tid & 63) * 4;
    const int r0 = (tid >> 6) * 16;
    const int r_st = tid & 63;
    const int kb = (tid >> 6) * 8;

    float acc[16][4];
    #pragma unroll
    for (int i = 0; i < 16; ++i)
        #pragma unroll
        for (int j = 0; j < 4; ++j) acc[i][j] = 0.f;

    for (int kc = 0; kc < 8; ++kc) {
        if (kc) __syncthreads();
        {
            const float* p = X + (size_t)(Rbase + r_st) * 256 + kc * 32 + kb;
            float4 a = *(const float4*)p;
            float4 b = *(const float4*)(p + 4);
            Xs[kb + 0][r_st] = a.x; Xs[kb + 1][r_st] = a.y;
            Xs[kb + 2][r_st] = a.z; Xs[kb + 3][r_st] = a.w;
            Xs[kb + 4][r_st] = b.x; Xs[kb + 5][r_st] = b.y;
            Xs[kb + 6][r_st] = b.z; Xs[kb + 7][r_st] = b.w;
        }
        #pragma unroll
        for (int m = 0; m < 8; ++m) {
            int f  = tid + m * 256;
            int kk = f >> 6;
            int cc = (f & 63) * 4;
            *(float4*)&Ws[kk][cc] = *(const float4*)&W[(size_t)(kc * 32 + kk) * 256 + cc];
        }
        __syncthreads();
        #pragma unroll 8
        for (int kk = 0; kk < 32; ++kk) {
            float4 w = *(const float4*)&Ws[kk][c0];
            #pragma unroll
            for (int i = 0; i < 4; ++i) {
                float4 x = *(const float4*)&Xs[kk][r0 + 4 * i];
                FMA_ROW(4 * i + 0, x.x)
                FMA_ROW(4 * i + 1, x.y)
                FMA_ROW(4 * i + 2, x.z)
                FMA_ROW(4 * i + 3, x.w)
            }
        }
    }
    float4 bv = bias ? *(const float4*)&bias[c0] : make_float4(0.f, 0.f, 0.f, 0.f);
    #pragma unroll
    for (int i = 0; i < 16; ++i) {
        int R = Rbase + r0 + i;
        ushort4 u;
        u.x = f2bf(acc[i][0] + bv.x);
        u.y = f2bf(acc[i][1] + bv.y);
        u.z = f2bf(acc[i][2] + bv.z);
        u.w = f2bf(acc[i][3] + bv.w);
        *(ushort4*)&Y[(size_t)R * 256 + c0] = u;
    }
}

// ---- edge kernel A (MLP2): hidden=ELU(P[j]+Q[i]); x2=ELU(hidden@W2+b2) ----
__global__ __launch_bounds__(256, 4)
void edge_mlp2(const ushort_t* __restrict__ Pb, const ushort_t* __restrict__ Qb,
               const ushort_t* __restrict__ W2T,   // [chan][256] bf16
               const float* __restrict__ b2,
               ushort_t* __restrict__ Y, float* __restrict__ aux)
{
    __shared__ ushort_t As[64][264];    // hidden, then x2 park
    const int tid = threadIdx.x;
    const int w = tid >> 6;
    const int l = tid & 63;
    const int ln15 = l & 15;
    const int q = l >> 4;
    const int klane = 8 * q;
    const int Rbase = blockIdx.x * 64;

    // phase 1: hidden tile (coalesced row gathers of P/Q, elementwise ELU)
    {
        int row = tid >> 2;
        int R = Rbase + row;
        int b = R / E_EDGES;
        int e = R - b * E_EDGES;
        int i = e / 99;
        int k = e - 99 * i;
        int j = k + (k >= i ? 1 : 0);
        const ushort_t* prow = Pb + (size_t)(b * NNODE + j) * HID;
        const ushort_t* qrow = Qb + (size_t)(b * NNODE + i) * HID;
        int off = (tid & 3) * 8;
        #pragma unroll
        for (int u = 0; u < 8; ++u) {
            int o = off + u * 32;
            union { uint4 v; ushort_t s[8]; } pu, qu, hu;
            pu.v = *(const uint4*)(prow + o);
            qu.v = *(const uint4*)(qrow + o);
            #pragma unroll
            for (int x = 0; x < 8; ++x)
                hu.s[x] = f2bf(elu_f(bf2f(pu.s[x]) + bf2f(qu.s[x])));
            *(uint4*)&As[row][o] = hu.v;
        }
    }
    __syncthreads();

    // GEMM: acc = hidden @ W2 (swapped-operand MFMA, W-frags from L2)
    f32x4 acc[4][4];
    #pragma unroll
    for (int r = 0; r < 4; ++r)
        #pragma unroll
        for (int c = 0; c < 4; ++c)
            acc[r][c][0] = acc[r][c][1] = acc[r][c][2] = acc[r][c][3] = 0.f;
    int wch[4];
    #pragma unroll
    for (int c = 0; c < 4; ++c) wch[c] = (w * 64 + 16 * c + ln15) * 256;
    {
        bf16x8 wf0[4];
        #pragma unroll
        for (int c = 0; c < 4; ++c)
            wf0[c] = *(const bf16x8*)(W2T + wch[c] + klane);
        #pragma unroll
        for (int kc = 0; kc < 8; ++kc) {
            bf16x8 wf1[4];
            if (kc < 7) {
                #pragma unroll
                for (int c = 0; c < 4; ++c)
                    wf1[c] = *(const bf16x8*)(W2T + wch[c] + (kc + 1) * 32 + klane);
            }
            bf16x8 af[4];
            #pragma unroll
            for (int r = 0; r < 4; ++r)
                af[r] = *(const bf16x8*)&As[16 * r + ln15][kc * 32 + klane];
            #pragma unroll
            for (int r = 0; r < 4; ++r)
                #pragma unroll
                for (int c = 0; c < 4; ++c)
                    acc[r][c] = __builtin_amdgcn_mfma_f32_16x16x32_bf16(wf0[c], af[r], acc[r][c], 0, 0, 0);
            #pragma unroll
            for (int c = 0; c < 4; ++c) wf0[c] = wf1[c];
        }
    }
    __syncthreads();    // hidden reads done

    // park x2 = ELU(acc + b2)
    #pragma unroll
    for (int c = 0; c < 4; ++c) {
        float4 bv = *(const float4*)&b2[w * 64 + 16 * c + 4 * q];
        #pragma unroll
        for (int r = 0; r < 4; ++r) {
            ushort4 u;
            u.x = f2bf(elu_f(acc[r][c][0] + bv.x));
            u.y = f2bf(elu_f(acc[r][c][1] + bv.y));
            u.z = f2bf(elu_f(acc[r][c][2] + bv.z));
            u.w = f2bf(elu_f(acc[r][c][3] + bv.w));
            *(ushort4*)&As[16 * r + ln15][w * 64 + 16 * c + 4 * q] = u;
        }
    }
    __syncthreads();

    // coalesced global write
    #pragma unroll
    for (int m = 0; m < 8; ++m) {
        int ch = tid + m * 256;
        int row = ch >> 5;
        int o = (ch & 31) * 8;
        *(uint4*)&Y[((size_t)(Rbase + row)) * 256 + o] = *(const uint4*)&As[row][o];
    }

    // e2n epilogue (atomics are cold here: <=3 adds per address)
    {
        int c = tid;
        int bn = Rbase / 99;
        int left = 99 - (Rbase - bn * 99);
        float s = 0.f;
        for (int r = 0; r < 64; ++r) {
            s += bf2f(As[r][c]);
            if (--left == 0) { atomicAdd(&aux[(size_t)bn * 256 + c], s); s = 0.f; ++bn; left = 99; }
        }
        atomicAdd(&aux[(size_t)bn * 256 + c], s);
    }
}

// ---- edge kernel B (MLP4): pre=P[j]+Q[i]+x2@W4a3; x4=ELU(ELU(pre)@W4b+b2) -
// BN stats: per-block bf16 partials (NO hot atomics).
__global__ __launch_bounds__(256, 4)
void edge_mlp4(const ushort_t* __restrict__ Pb, const ushort_t* __restrict__ Qb,
               const ushort_t* __restrict__ X2,
               const ushort_t* __restrict__ WaT,   // [chan][256] bf16
               const ushort_t* __restrict__ WbT,   // [chan][256] bf16
               const float* __restrict__ b2,
               ushort_t* __restrict__ Y, ushort_t* __restrict__ pstat)
{
    __shared__ ushort_t As[64][264];    // x2 tile -> hidden -> x4 park
    const int tid = threadIdx.x;
    const int w = tid >> 6;
    const int l = tid & 63;
    const int ln15 = l & 15;
    const int q = l >> 4;
    const int klane = 8 * q;
    const int Rbase = blockIdx.x * 64;

    // phase 0: stage x2 tile (coalesced)
    {
        int row = tid >> 2;
        const ushort_t* xrow = X2 + (size_t)(Rbase + row) * 256;
        int off = (tid & 3) * 8;
        #pragma unroll
        for (int u = 0; u < 8; ++u) {
            int o = off + u * 32;
            *(uint4*)&As[row][o] = *(const uint4*)(xrow + o);
        }
    }

    // per-lane P/Q row offsets for its 4 row-tiles
    int oP[4], oQ[4];
    #pragma unroll
    for (int r = 0; r < 4; ++r) {
        int R = Rbase + 16 * r + ln15;
        int b = R / E_EDGES;
        int e = R - b * E_EDGES;
        int i = e / 99;
        int k = e - 99 * i;
        int j = k + (k >= i ? 1 : 0);
        oP[r] = (b * NNODE + j) * HID;
        oQ[r] = (b * NNODE + i) * HID;
    }
    __syncthreads();

    f32x4 acc[4][4];
    int wch[4];
    #pragma unroll
    for (int c = 0; c < 4; ++c) wch[c] = (w * 64 + 16 * c + ln15) * 256;

    // L1 GEMM: acc = x2tile @ W4a3
    #pragma unroll
    for (int r = 0; r < 4; ++r)
        #pragma unroll
        for (int c = 0; c < 4; ++c)
            acc[r][c][0] = acc[r][c][1] = acc[r][c][2] = acc[r][c][3] = 0.f;
    {
        bf16x8 wf0[4];
        #pragma unroll
        for (int c = 0; c < 4; ++c)
            wf0[c] = *(const bf16x8*)(WaT + wch[c] + klane);
        #pragma unroll
        for (int kc = 0; kc < 8; ++kc) {
            bf16x8 wf1[4];
            if (kc < 7) {
                #pragma unroll
                for (int c = 0; c < 4; ++c)
                    wf1[c] = *(const bf16x8*)(WaT + wch[c] + (kc + 1) * 32 + klane);
            }
            bf16x8 af[4];
            #pragma unroll
            for (int r = 0; r < 4; ++r)
                af[r] = *(const bf16x8*)&As[16 * r + ln15][kc * 32 + klane];
            #pragma unroll
            for (int r = 0; r < 4; ++r)
                #pragma unroll
                for (int c = 0; c < 4; ++c)
                    acc[r][c] = __builtin_amdgcn_mfma_f32_16x16x32_bf16(wf0[c], af[r], acc[r][c], 0, 0, 0);
            #pragma unroll
            for (int c = 0; c < 4; ++c) wf0[c] = wf1[c];
        }
    }
    __syncthreads();    // x2 tile reads done

    // hidden = ELU(acc + P[j] + Q[i]) -> As   (P/Q: per-lane ushort4 from L2)
    #pragma unroll
    for (int c = 0; c < 4; ++c) {
        int ch = w * 64 + 16 * c + 4 * q;
        #pragma unroll
        for (int r = 0; r < 4; ++r) {
            union { ushort4 v; ushort_t s[4]; } pu, qu;
            pu.v = *(const ushort4*)(Pb + oP[r] + ch);
            qu.v = *(const ushort4*)(Qb + oQ[r] + ch);
            ushort4 u;
            u.x = f2bf(elu_f(acc[r][c][0] + bf2f(pu.s[0]) + bf2f(qu.s[0])));
            u.y = f2bf(elu_f(acc[r][c][1] + bf2f(pu.s[1]) + bf2f(qu.s[1])));
            u.z = f2bf(elu_f(acc[r][c][2] + bf2f(pu.s[2]) + bf2f(qu.s[2])));
            u.w = f2bf(elu_f(acc[r][c][3] + bf2f(pu.s[3]) + bf2f(qu.s[3])));
            *(ushort4*)&As[16 * r + ln15][ch] = u;
        }
    }
    __syncthreads();

    // L2 GEMM: acc = hidden @ W4b
    #pragma unroll
    for (int r = 0; r < 4; ++r)
        #pragma unroll
        for (int c = 0; c < 4; ++c)
            acc[r][c][0] = acc[r][c][1] = acc[r][c][2] = acc[r][c][3] = 0.f;
    {
        bf16x8 wf0[4];
        #pragma unroll
        for (int c = 0; c < 4; ++c)
            wf0[c] = *(const bf16x8*)(WbT + wch[c] + klane);
        #pragma unroll
        for (int kc = 0; kc < 8; ++kc) {
            bf16x8 wf1[4];
            if (kc < 7) {
                #pragma unroll
                for (int c = 0; c < 4; ++c)
                    wf1[c] = *(const bf16x8*)(WbT + wch[c] + (kc + 1) * 32 + klane);
            }
            bf16x8 af[4];
            #pragma unroll
            for (int r = 0; r < 4; ++r)
                af[r] = *(const bf16x8*)&As[16 * r + ln15][kc * 32 + klane];
            #pragma unroll
            for (int r = 0; r < 4; ++r)
                #pragma unroll
                for (int c = 0; c < 4; ++c)
                    acc[r][c] = __builtin_amdgcn_mfma_f32_16x16x32_bf16(wf0[c], af[r], acc[r][c], 0, 0, 0);
            #pragma unroll
            for (int c = 0; c < 4; ++c) wf0[c] = wf1[c];
        }
    }
    __syncthreads();    // hidden reads done before park overwrite

    // x4 = ELU(acc + b2) -> As park
    #pragma unroll
    for (int c = 0; c < 4; ++c) {
        float4 bv = *(const float4*)&b2[w * 64 + 16 * c + 4 * q];
        #pragma unroll
        for (int r = 0; r < 4; ++r) {
            ushort4 u;
            u.x = f2bf(elu_f(acc[r][c][0] + bv.x));
            u.y = f2bf(elu_f(acc[r][c][1] + bv.y));
            u.z = f2bf(elu_f(acc[r][c][2] + bv.z));
            u.w = f2bf(elu_f(acc[r][c][3] + bv.w));
            *(ushort4*)&As[16 * r + ln15][w * 64 + 16 * c + 4 * q] = u;
        }
    }
    __syncthreads();

    // coalesced global write (in-place over X2 rows of this block)
    #pragma unroll
    for (int m = 0; m < 8; ++m) {
        int ch = tid + m * 256;
        int row = ch >> 5;
        int o = (ch & 31) * 8;
        *(uint4*)&Y[((size_t)(Rbase + row)) * 256 + o] = *(const uint4*)&As[row][o];
    }

    // BN-stats: per-block bf16 partials, coalesced (no hot atomics!)
    {
        int c = tid;
        float s = 0.f, q2 = 0.f;
        for (int r = 0; r < 64; ++r) {
            float v = bf2f(As[r][c]);
            s += v;
            q2 = fmaf(v, v, q2);
        }
        size_t base = (size_t)blockIdx.x * 512;
        pstat[base + c]       = f2bf(s);
        pstat[base + 256 + c] = f2bf(q2);
    }
}

// ---- reduce per-block partials -> stats (64 blocks: 64 atomics/address) ---
__global__ __launch_bounds__(256)
void reduce_stats(const ushort_t* __restrict__ pstat, float* __restrict__ stats)
{
    int c = threadIdx.x;
    float s = 0.f, q = 0.f;
    for (int b = blockIdx.x; b < NBLK; b += 64) {
        size_t base = (size_t)b * 512;
        s += bf2f(pstat[base + c]);
        q += bf2f(pstat[base + 256 + c]);
    }
    atomicAdd(&stats[c], s);
    atomicAdd(&stats[256 + c], q);
}

// ---- fold BN + fc into Wfold[256][2], bfold[2] ----------------------------
__global__ __launch_bounds__(256)
void fold_kernel(const float* __restrict__ stats,
                 const float* __restrict__ gamma, const float* __restrict__ beta,
                 const float* __restrict__ fcW, const float* __restrict__ fcb,
                 float* __restrict__ fold)
{
    __shared__ float red0[256], red1[256];
    int c = threadIdx.x;
    float mean  = stats[c] * (1.f / M_BIG);
    float var   = stats[256 + c] * (1.f / M_BIG) - mean * mean;
    float inv   = rsqrtf(var + 1e-5f);
    float scale = inv * gamma[c];
    float sh    = beta[c] - mean * scale;
    float w0 = fcW[c * 2 + 0], w1 = fcW[c * 2 + 1];
    fold[c * 2 + 0] = scale * w0;
    fold[c * 2 + 1] = scale * w1;
    red0[c] = sh * w0;
    red1[c] = sh * w1;
    __syncthreads();
    for (int off = 128; off > 0; off >>= 1) {
        if (c < off) { red0[c] += red0[c + off]; red1[c] += red1[c + off]; }
        __syncthreads();
    }
    if (c == 0) {
        fold[512] = red0[0] + fcb[0];
        fold[513] = red1[0] + fcb[1];
    }
}

// ---- final: out[R][2] = x4_row . Wfold + bfold  (32 lanes per row, uint4) -
__global__ __launch_bounds__(256)
void final_kernel(const ushort_t* __restrict__ x4, const float* __restrict__ fold,
                  float* __restrict__ out)
{
    int tid  = threadIdx.x;
    int l32  = tid & 31;
    int g    = tid >> 5;          // 8 row-groups per block
    int R = blockIdx.x * 8 + g;
    int c0 = l32 * 8;
    union { uint4 qv; ushort_t s[8]; } u;
    u.qv = *(const uint4*)(x4 + (size_t)R * 256 + c0);
    float a0 = 0.f, a1 = 0.f;
    #pragma unroll
    for (int j = 0; j < 8; ++j) {
        float v = bf2f(u.s[j]);
        a0 = fmaf(v, fold[(c0 + j) * 2 + 0], a0);
        a1 = fmaf(v, fold[(c0 + j) * 2 + 1], a1);
    }
    #pragma unroll
    for (int off = 16; off > 0; off >>= 1) {
        a0 += __shfl_down(a0, off);
        a1 += __shfl_down(a1, off);
    }
    if (l32 == 0) {
        out[(size_t)R * 2 + 0] = a0 + fold[512];
        out[(size_t)R * 2 + 1] = a1 + fold[513];
    }
}

extern "C" void kernel_launch(void* const* d_in, const int* in_sizes, int n_in,
                              void* d_out, int out_size, void* d_ws, size_t ws_size,
                              hipStream_t stream)
{
    (void)in_sizes; (void)n_in; (void)out_size; (void)ws_size;

    const float* inputs = (const float*)d_in[0];
    const float* m1W1 = (const float*)d_in[3];
    const float* m1b1 = (const float*)d_in[4];
    const float* m1W2 = (const float*)d_in[5];
    const float* m1b2 = (const float*)d_in[6];
    const float* m2W1 = (const float*)d_in[7];
    const float* m2b1 = (const float*)d_in[8];
    const float* m2W2 = (const float*)d_in[9];
    const float* m2b2 = (const float*)d_in[10];
    const float* m3W1 = (const float*)d_in[11];
    const float* m3b1 = (const float*)d_in[12];
    const float* m3W2 = (const float*)d_in[13];
    const float* m3b2 = (const float*)d_in[14];
    const float* m4W1 = (const float*)d_in[15];
    const float* m4b1 = (const float*)d_in[16];
    const float* m4W2 = (const float*)d_in[17];
    const float* m4b2 = (const float*)d_in[18];
    const float* gamma = (const float*)d_in[19];
    const float* beta  = (const float*)d_in[20];
    const float* fcW   = (const float*)d_in[21];
    const float* fcb   = (const float*)d_in[22];
    float* out = (float*)d_out;

    // ---- workspace layout (~173 MB) ----
    char* ws = (char*)d_ws;
    const size_t BIGB  = (size_t)M_BIG * 256 * 2;     // 162,201,600
    const size_t SMALL = (size_t)M_SMALL * 256 * 4;   // 3,276,800 (fp32 small)
    const size_t HB    = (size_t)M_SMALL * 256 * 2;   // 1,638,400 (bf16 small)
    ushort_t* bigX     = (ushort_t*)ws;                       // x2 then x4
    float*    hsm      = (float*)(ws + BIGB);                 // h1 then h3 (fp32)
    float*    incoming = (float*)(ws + BIGB + SMALL);
    // pstat (4950*512 bf16 = 5.07 MB) overlaps hsm+incoming: both are dead
    // by the time edge_mlp4 runs.
    ushort_t* pstat    = (ushort_t*)(ws + BIGB);
    ushort_t* Pbuf     = (ushort_t*)(ws + BIGB + 2 * SMALL);
    ushort_t* Qbuf     = (ushort_t*)(ws + BIGB + 2 * SMALL + HB);
    float*    stats    = (float*)(ws + BIGB + 2 * SMALL + 2 * HB);
    float*    fold     = stats + 512;
    ushort_t* w2t      = (ushort_t*)(ws + BIGB + 2 * SMALL + 2 * HB + 8192);
    ushort_t* w4at     = w2t + 256 * 256;     // W4a3 (rows 512..767 of m4W1)
    ushort_t* w4bt     = w4at + 256 * 256;

    hipMemsetAsync(stats, 0, 2048, stream);
    hipMemsetAsync(incoming, 0, SMALL, stream);

    dim3 blk(256);
    wcvt3_kernel<<<48, blk, 0, stream>>>(m2W2, m4W1 + 512 * 256, m4W2, w2t, w4at, w4bt);
    // MLP1 -> h1 (fp32)
    fused_small<<<M_SMALL / 64, blk, 0, stream>>>(inputs, 200, 1.f, m1W1, m1b1, m1W2, m1b2, hsm);
    // P2 = h1@W1a + b1, Q2 = h1@W1b
    pq_gemm<<<100, blk, 0, stream>>>(hsm, m2W1, m2W1 + 256 * 256, m2b1, Pbuf, Qbuf);
    // edge MLP2 -> x2 + e2n sums
    edge_mlp2<<<M_BIG / 64, blk, 0, stream>>>(Pbuf, Qbuf, w2t, m2b2, bigX, incoming);
    // MLP3 (incoming/9900) -> h3 (fp32)
    fused_small<<<M_SMALL / 64, blk, 0, stream>>>(incoming, 256, 1.f / 9900.f, m3W1, m3b1, m3W2, m3b2, hsm);
    // P4 = h3@W4a1 + b1, Q4 = h3@W4a2
    pq_gemm<<<100, blk, 0, stream>>>(hsm, m4W1, m4W1 + 256 * 256, m4b1, Pbuf, Qbuf);
    // edge MLP4 -> x4 (in-place) + per-block stats partials
    edge_mlp4<<<M_BIG / 64, blk, 0, stream>>>(Pbuf, Qbuf, bigX, w4at, w4bt, m4b2, bigX, pstat);
    // partials -> stats -> fold -> final
    reduce_stats<<<64, blk, 0, stream>>>(pstat, stats);
    fold_kernel<<<1, blk, 0, stream>>>(stats, gamma, beta, fcW, fcb, fold);
    final_kernel<<<M_BIG / 8, blk, 0, stream>>>(bigX, fold, out);
}

// Round 9
// 857.774 us; speedup vs baseline: 1.0075x; 1.0075x over previous
//
#include <hip/hip_runtime.h>
#include <math.h>

// ---------------------------------------------------------------------------
// MLPEncoder (NRI encoder) on MI355X — round 9: de-serialize the load chains.
//   R8 structure kept. Changes:
//   - edge_mlp2 phase-1: all 16 P/Q uint4 loads batched into registers
//     before compute (was load->use per iteration = 16 serial round-trips).
//   - edge_mlp4: phase-0 stage loads batched; hidden-phase P/Q loads batched
//     per column-tile with 1-deep pipeline (8 loads in flight).
//   - e2n / BN-stats epilogues: 64 threads x ushort4 column scans (4x fewer
//     LDS wave-instructions than 256 x scalar b16).
// ---------------------------------------------------------------------------

typedef unsigned short ushort_t;
typedef __bf16 bf16x8 __attribute__((ext_vector_type(8)));
typedef float  f32x4  __attribute__((ext_vector_type(4)));

#define E_EDGES 9900
#define NNODE   100
#define HID     256
#define M_BIG   316800
#define M_SMALL 3200
#define NBLK    (M_BIG / 64)   /* 4950 */

__device__ __forceinline__ float bf2f(ushort_t u) {
    union { unsigned int i; float f; } v; v.i = ((unsigned int)u) << 16; return v.f;
}
__device__ __forceinline__ ushort_t f2bf(float f) {
    union { float f; unsigned int i; } v; v.f = f;
    return (ushort_t)((v.i + 0x7fffu + ((v.i >> 16) & 1u)) >> 16);   // RNE
}
__device__ __forceinline__ float elu_f(float x) {
    return x > 0.f ? x : (__expf(x) - 1.f);
}

// ---- convert+transpose 3 [256,256] fp32 matrices -> bf16 WT[chan][256] ----
__global__ __launch_bounds__(256)
void wcvt3_kernel(const float* __restrict__ W0, const float* __restrict__ W1,
                  const float* __restrict__ W2,
                  ushort_t* __restrict__ T0, ushort_t* __restrict__ T1,
                  ushort_t* __restrict__ T2)
{
    int bid = blockIdx.x;
    const float* W; ushort_t* WT; int tile;
    if (bid < 16)      { W = W0; WT = T0; tile = bid; }
    else if (bid < 32) { W = W1; WT = T1; tile = bid - 16; }
    else               { W = W2; WT = T2; tile = bid - 32; }
    int k0 = (tile >> 2) * 64, c0 = (tile & 3) * 64;
    __shared__ float S[64][65];
    int t = threadIdx.x;
    #pragma unroll
    for (int i = 0; i < 16; ++i) {
        int idx = t + i * 256;
        S[idx >> 6][idx & 63] = W[(size_t)(k0 + (idx >> 6)) * 256 + c0 + (idx & 63)];
    }
    __syncthreads();
    int col = t & 63;
    int kb  = (t >> 6) * 16;
    ushort_t* dst = WT + (size_t)(c0 + col) * 256 + k0 + kb;
    #pragma unroll
    for (int jj = 0; jj < 4; ++jj) {
        ushort4 u;
        u.x = f2bf(S[kb + 4 * jj + 0][col]);
        u.y = f2bf(S[kb + 4 * jj + 1][col]);
        u.z = f2bf(S[kb + 4 * jj + 2][col]);
        u.w = f2bf(S[kb + 4 * jj + 3][col]);
        *(ushort4*)(dst + 4 * jj) = u;
    }
}

// ---- fused small 2-layer fp32 MLP: X[3200,K0] -> ELU MLP -> fp32 [3200,256]
#define FMA_ROW(ri, xs) \
    acc[ri][0] = fmaf(xs, w.x, acc[ri][0]); \
    acc[ri][1] = fmaf(xs, w.y, acc[ri][1]); \
    acc[ri][2] = fmaf(xs, w.z, acc[ri][2]); \
    acc[ri][3] = fmaf(xs, w.w, acc[ri][3]);

__global__ __launch_bounds__(256, 2)
void fused_small(const float* __restrict__ X, int K0, float xscale,
                 const float* __restrict__ W1, const float* __restrict__ b1,
                 const float* __restrict__ W2, const float* __restrict__ b2,
                 float* __restrict__ Yf)
{
    __shared__ float Xs[32][68];
    __shared__ float Ws[32][256];
    __shared__ float Hs[64][257];
    const int tid = threadIdx.x;
    const int Rbase = blockIdx.x * 64;
    const int c0 = (tid & 63) * 4;
    const int r0 = (tid >> 6) * 16;
    const int r_st = tid & 63;
    const int kb = (tid >> 6) * 8;

    float acc[16][4];
    #pragma unroll
    for (int i = 0; i < 16; ++i)
        #pragma unroll
        for (int j = 0; j < 4; ++j) acc[i][j] = 0.f;

    const int nch = (K0 + 31) >> 5;
    for (int kc = 0; kc < nch; ++kc) {
        if (kc) __syncthreads();
        {
            int kg = kc * 32 + kb;
            const float* p = X + (size_t)(Rbase + r_st) * K0 + kg;
            float v[8];
            if (kg + 8 <= K0) {
                float4 a = *(const float4*)p;
                float4 b = *(const float4*)(p + 4);
                v[0]=a.x; v[1]=a.y; v[2]=a.z; v[3]=a.w;
                v[4]=b.x; v[5]=b.y; v[6]=b.z; v[7]=b.w;
            } else {
                #pragma unroll
                for (int j = 0; j < 8; ++j) v[j] = (kg + j < K0) ? p[j] : 0.f;
            }
            #pragma unroll
            for (int j = 0; j < 8; ++j) Xs[kb + j][r_st] = v[j];
        }
        #pragma unroll
        for (int m = 0; m < 8; ++m) {
            int f  = tid + m * 256;
            int kk = f >> 6;
            int cc = (f & 63) * 4;
            int kg = kc * 32 + kk;
            float4 w = (kg < K0) ? *(const float4*)&W1[(size_t)kg * 256 + cc]
                                 : make_float4(0.f, 0.f, 0.f, 0.f);
            *(float4*)&Ws[kk][cc] = w;
        }
        __syncthreads();
        #pragma unroll 8
        for (int kk = 0; kk < 32; ++kk) {
            float4 w = *(const float4*)&Ws[kk][c0];
            #pragma unroll
            for (int i = 0; i < 4; ++i) {
                float4 x = *(const float4*)&Xs[kk][r0 + 4 * i];
                FMA_ROW(4 * i + 0, x.x)
                FMA_ROW(4 * i + 1, x.y)
                FMA_ROW(4 * i + 2, x.z)
                FMA_ROW(4 * i + 3, x.w)
            }
        }
    }
    {
        float4 bv = *(const float4*)&b1[c0];
        #pragma unroll
        for (int i = 0; i < 16; ++i) {
            Hs[r0 + i][c0 + 0] = elu_f(acc[i][0] * xscale + bv.x);
            Hs[r0 + i][c0 + 1] = elu_f(acc[i][1] * xscale + bv.y);
            Hs[r0 + i][c0 + 2] = elu_f(acc[i][2] * xscale + bv.z);
            Hs[r0 + i][c0 + 3] = elu_f(acc[i][3] * xscale + bv.w);
        }
    }
    #pragma unroll
    for (int i = 0; i < 16; ++i)
        #pragma unroll
        for (int j = 0; j < 4; ++j) acc[i][j] = 0.f;
    for (int kc = 0; kc < 8; ++kc) {
        __syncthreads();
        {
            #pragma unroll
            for (int j = 0; j < 8; ++j) Xs[kb + j][r_st] = Hs[r_st][kc * 32 + kb + j];
        }
        #pragma unroll
        for (int m = 0; m < 8; ++m) {
            int f  = tid + m * 256;
            int kk = f >> 6;
            int cc = (f & 63) * 4;
            *(float4*)&Ws[kk][cc] = *(const float4*)&W2[(size_t)(kc * 32 + kk) * 256 + cc];
        }
        __syncthreads();
        #pragma unroll 8
        for (int kk = 0; kk < 32; ++kk) {
            float4 w = *(const float4*)&Ws[kk][c0];
            #pragma unroll
            for (int i = 0; i < 4; ++i) {
                float4 x = *(const float4*)&Xs[kk][r0 + 4 * i];
                FMA_ROW(4 * i + 0, x.x)
                FMA_ROW(4 * i + 1, x.y)
                FMA_ROW(4 * i + 2, x.z)
                FMA_ROW(4 * i + 3, x.w)
            }
        }
    }
    {
        float4 bv = *(const float4*)&b2[c0];
        #pragma unroll
        for (int i = 0; i < 16; ++i) {
            int R = Rbase + r0 + i;
            *(float4*)&Yf[(size_t)R * 256 + c0] = make_float4(
                elu_f(acc[i][0] + bv.x), elu_f(acc[i][1] + bv.y),
                elu_f(acc[i][2] + bv.z), elu_f(acc[i][3] + bv.w));
        }
    }
}

// ---- P/Q partial GEMMs: P = X@Wa + biasA (no act), Q = X@Wb (bf16 out) ----
__global__ __launch_bounds__(256, 2)
void pq_gemm(const float* __restrict__ X,
             const float* __restrict__ Wa, const float* __restrict__ Wb_,
             const float* __restrict__ biasA,
             ushort_t* __restrict__ Yp, ushort_t* __restrict__ Yq)
{
    const int bid = blockIdx.x;
    const float* W; const float* bias; ushort_t* Y; int Rbase;
    if (bid < 50) { W = Wa;  bias = biasA;  Y = Yp; Rbase = bid * 64; }
    else          { W = Wb_; bias = nullptr; Y = Yq; Rbase = (bid - 50) * 64; }

    __shared__ float Xs[32][68];
    __shared__ float Ws[32][256];
    const int tid = threadIdx.x;
    const int c0 = (tid & 63) * 4;
    const int r0 = (tid >> 6) * 16;
    const int r_st = tid & 63;
    const int kb = (tid >> 6) * 8;

    float acc[16][4];
    #pragma unroll
    for (int i = 0; i < 16; ++i)
        #pragma unroll
        for (int j = 0; j < 4; ++j) acc[i][j] = 0.f;

    for (int kc = 0; kc < 8; ++kc) {
        if (kc) __syncthreads();
        {
            const float* p = X + (size_t)(Rbase + r_st) * 256 + kc * 32 + kb;
            float4 a = *(const float4*)p;
            float4 b = *(const float4*)(p + 4);
            Xs[kb + 0][r_st] = a.x; Xs[kb + 1][r_st] = a.y;
            Xs[kb + 2][r_st] = a.z; Xs[kb + 3][r_st] = a.w;
            Xs[kb + 4][r_st] = b.x; Xs[kb + 5][r_st] = b.y;
            Xs[kb + 6][r_st] = b.z; Xs[kb + 7][r_st] = b.w;
        }
        #pragma unroll
        for (int m = 0; m < 8; ++m) {
            int f  = tid + m * 256;
            int kk = f >> 6;
            int cc = (f & 63) * 4;
            *(float4*)&Ws[kk][cc] = *(const float4*)&W[(size_t)(kc * 32 + kk) * 256 + cc];
        }
        __syncthreads();
        #pragma unroll 8
        for (int kk = 0; kk < 32; ++kk) {
            float4 w = *(const float4*)&Ws[kk][c0];
            #pragma unroll
            for (int i = 0; i < 4; ++i) {
                float4 x = *(const float4*)&Xs[kk][r0 + 4 * i];
                FMA_ROW(4 * i + 0, x.x)
                FMA_ROW(4 * i + 1, x.y)
                FMA_ROW(4 * i + 2, x.z)
                FMA_ROW(4 * i + 3, x.w)
            }
        }
    }
    float4 bv = bias ? *(const float4*)&bias[c0] : make_float4(0.f, 0.f, 0.f, 0.f);
    #pragma unroll
    for (int i = 0; i < 16; ++i) {
        int R = Rbase + r0 + i;
        ushort4 u;
        u.x = f2bf(acc[i][0] + bv.x);
        u.y = f2bf(acc[i][1] + bv.y);
        u.z = f2bf(acc[i][2] + bv.z);
        u.w = f2bf(acc[i][3] + bv.w);
        *(ushort4*)&Y[(size_t)R * 256 + c0] = u;
    }
}

// ---- edge kernel A (MLP2): hidden=ELU(P[j]+Q[i]); x2=ELU(hidden@W2+b2) ----
__global__ __launch_bounds__(256, 4)
void edge_mlp2(const ushort_t* __restrict__ Pb, const ushort_t* __restrict__ Qb,
               const ushort_t* __restrict__ W2T,   // [chan][256] bf16
               const float* __restrict__ b2,
               ushort_t* __restrict__ Y, float* __restrict__ aux)
{
    __shared__ ushort_t As[64][264];    // hidden, then x2 park
    const int tid = threadIdx.x;
    const int w = tid >> 6;
    const int l = tid & 63;
    const int ln15 = l & 15;
    const int q = l >> 4;
    const int klane = 8 * q;
    const int Rbase = blockIdx.x * 64;

    // phase 1: hidden tile — ALL 16 loads batched, then compute/write
    {
        int row = tid >> 2;
        int R = Rbase + row;
        int b = R / E_EDGES;
        int e = R - b * E_EDGES;
        int i = e / 99;
        int k = e - 99 * i;
        int j = k + (k >= i ? 1 : 0);
        const ushort_t* prow = Pb + (size_t)(b * NNODE + j) * HID;
        const ushort_t* qrow = Qb + (size_t)(b * NNODE + i) * HID;
        int off = (tid & 3) * 8;
        uint4 pv[8], qv[8];
        #pragma unroll
        for (int u = 0; u < 8; ++u) {
            int o = off + u * 32;
            pv[u] = *(const uint4*)(prow + o);
            qv[u] = *(const uint4*)(qrow + o);
        }
        #pragma unroll
        for (int u = 0; u < 8; ++u) {
            int o = off + u * 32;
            union { uint4 v; ushort_t s[8]; } pu, qu, hu;
            pu.v = pv[u]; qu.v = qv[u];
            #pragma unroll
            for (int x = 0; x < 8; ++x)
                hu.s[x] = f2bf(elu_f(bf2f(pu.s[x]) + bf2f(qu.s[x])));
            *(uint4*)&As[row][o] = hu.v;
        }
    }
    __syncthreads();

    // GEMM: acc = hidden @ W2 (swapped-operand MFMA, W-frags from L2)
    f32x4 acc[4][4];
    #pragma unroll
    for (int r = 0; r < 4; ++r)
        #pragma unroll
        for (int c = 0; c < 4; ++c)
            acc[r][c][0] = acc[r][c][1] = acc[r][c][2] = acc[r][c][3] = 0.f;
    int wch[4];
    #pragma unroll
    for (int c = 0; c < 4; ++c) wch[c] = (w * 64 + 16 * c + ln15) * 256;
    {
        bf16x8 wf0[4];
        #pragma unroll
        for (int c = 0; c < 4; ++c)
            wf0[c] = *(const bf16x8*)(W2T + wch[c] + klane);
        #pragma unroll
        for (int kc = 0; kc < 8; ++kc) {
            bf16x8 wf1[4];
            if (kc < 7) {
                #pragma unroll
                for (int c = 0; c < 4; ++c)
                    wf1[c] = *(const bf16x8*)(W2T + wch[c] + (kc + 1) * 32 + klane);
            }
            bf16x8 af[4];
            #pragma unroll
            for (int r = 0; r < 4; ++r)
                af[r] = *(const bf16x8*)&As[16 * r + ln15][kc * 32 + klane];
            #pragma unroll
            for (int r = 0; r < 4; ++r)
                #pragma unroll
                for (int c = 0; c < 4; ++c)
                    acc[r][c] = __builtin_amdgcn_mfma_f32_16x16x32_bf16(wf0[c], af[r], acc[r][c], 0, 0, 0);
            #pragma unroll
            for (int c = 0; c < 4; ++c) wf0[c] = wf1[c];
        }
    }
    __syncthreads();    // hidden reads done

    // park x2 = ELU(acc + b2)
    #pragma unroll
    for (int c = 0; c < 4; ++c) {
        float4 bv = *(const float4*)&b2[w * 64 + 16 * c + 4 * q];
        #pragma unroll
        for (int r = 0; r < 4; ++r) {
            ushort4 u;
            u.x = f2bf(elu_f(acc[r][c][0] + bv.x));
            u.y = f2bf(elu_f(acc[r][c][1] + bv.y));
            u.z = f2bf(elu_f(acc[r][c][2] + bv.z));
            u.w = f2bf(elu_f(acc[r][c][3] + bv.w));
            *(ushort4*)&As[16 * r + ln15][w * 64 + 16 * c + 4 * q] = u;
        }
    }
    __syncthreads();

    // coalesced global write
    #pragma unroll
    for (int m = 0; m < 8; ++m) {
        int ch = tid + m * 256;
        int row = ch >> 5;
        int o = (ch & 31) * 8;
        *(uint4*)&Y[((size_t)(Rbase + row)) * 256 + o] = *(const uint4*)&As[row][o];
    }

    // e2n epilogue: 64 threads x 4 channels, ushort4 column scan
    if (tid < 64) {
        int c4 = tid * 4;
        int bn = Rbase / 99;
        int left = 99 - (Rbase - bn * 99);
        float s[4] = {0.f, 0.f, 0.f, 0.f};
        for (int r = 0; r < 64; ++r) {
            union { ushort4 v; ushort_t e[4]; } u;
            u.v = *(const ushort4*)&As[r][c4];
            #pragma unroll
            for (int g = 0; g < 4; ++g) s[g] += bf2f(u.e[g]);
            if (--left == 0) {
                #pragma unroll
                for (int g = 0; g < 4; ++g) {
                    atomicAdd(&aux[(size_t)bn * 256 + c4 + g], s[g]);
                    s[g] = 0.f;
                }
                ++bn; left = 99;
            }
        }
        #pragma unroll
        for (int g = 0; g < 4; ++g)
            atomicAdd(&aux[(size_t)bn * 256 + c4 + g], s[g]);
    }
}

// ---- edge kernel B (MLP4): pre=P[j]+Q[i]+x2@W4a3; x4=ELU(ELU(pre)@W4b+b2) -
__global__ __launch_bounds__(256, 4)
void edge_mlp4(const ushort_t* __restrict__ Pb, const ushort_t* __restrict__ Qb,
               const ushort_t* __restrict__ X2,
               const ushort_t* __restrict__ WaT,   // [chan][256] bf16
               const ushort_t* __restrict__ WbT,   // [chan][256] bf16
               const float* __restrict__ b2,
               ushort_t* __restrict__ Y, ushort_t* __restrict__ pstat)
{
    __shared__ ushort_t As[64][264];    // x2 tile -> hidden -> x4 park
    const int tid = threadIdx.x;
    const int w = tid >> 6;
    const int l = tid & 63;
    const int ln15 = l & 15;
    const int q = l >> 4;
    const int klane = 8 * q;
    const int Rbase = blockIdx.x * 64;

    // phase 0: stage x2 tile (batched loads, then writes)
    {
        int row = tid >> 2;
        const ushort_t* xrow = X2 + (size_t)(Rbase + row) * 256;
        int off = (tid & 3) * 8;
        uint4 xv[8];
        #pragma unroll
        for (int u = 0; u < 8; ++u) xv[u] = *(const uint4*)(xrow + off + u * 32);
        #pragma unroll
        for (int u = 0; u < 8; ++u) *(uint4*)&As[row][off + u * 32] = xv[u];
    }

    // per-lane P/Q row offsets for its 4 row-tiles
    int oP[4], oQ[4];
    #pragma unroll
    for (int r = 0; r < 4; ++r) {
        int R = Rbase + 16 * r + ln15;
        int b = R / E_EDGES;
        int e = R - b * E_EDGES;
        int i = e / 99;
        int k = e - 99 * i;
        int j = k + (k >= i ? 1 : 0);
        oP[r] = (b * NNODE + j) * HID;
        oQ[r] = (b * NNODE + i) * HID;
    }
    __syncthreads();

    f32x4 acc[4][4];
    int wch[4];
    #pragma unroll
    for (int c = 0; c < 4; ++c) wch[c] = (w * 64 + 16 * c + ln15) * 256;

    // L1 GEMM: acc = x2tile @ W4a3
    #pragma unroll
    for (int r = 0; r < 4; ++r)
        #pragma unroll
        for (int c = 0; c < 4; ++c)
            acc[r][c][0] = acc[r][c][1] = acc[r][c][2] = acc[r][c][3] = 0.f;
    {
        bf16x8 wf0[4];
        #pragma unroll
        for (int c = 0; c < 4; ++c)
            wf0[c] = *(const bf16x8*)(WaT + wch[c] + klane);
        #pragma unroll
        for (int kc = 0; kc < 8; ++kc) {
            bf16x8 wf1[4];
            if (kc < 7) {
                #pragma unroll
                for (int c = 0; c < 4; ++c)
                    wf1[c] = *(const bf16x8*)(WaT + wch[c] + (kc + 1) * 32 + klane);
            }
            bf16x8 af[4];
            #pragma unroll
            for (int r = 0; r < 4; ++r)
                af[r] = *(const bf16x8*)&As[16 * r + ln15][kc * 32 + klane];
            #pragma unroll
            for (int r = 0; r < 4; ++r)
                #pragma unroll
                for (int c = 0; c < 4; ++c)
                    acc[r][c] = __builtin_amdgcn_mfma_f32_16x16x32_bf16(wf0[c], af[r], acc[r][c], 0, 0, 0);
            #pragma unroll
            for (int c = 0; c < 4; ++c) wf0[c] = wf1[c];
        }
    }
    __syncthreads();    // x2 tile reads done

    // hidden = ELU(acc + P[j] + Q[i]) -> As
    // P/Q loads batched per column-tile (8 in flight), 1-deep pipeline.
    {
        ushort4 pv0[4], qv0[4], pv1[4], qv1[4];
        {
            int ch0 = w * 64 + 4 * q;
            #pragma unroll
            for (int r = 0; r < 4; ++r) {
                pv0[r] = *(const ushort4*)(Pb + oP[r] + ch0);
                qv0[r] = *(const ushort4*)(Qb + oQ[r] + ch0);
            }
        }
        #pragma unroll
        for (int c = 0; c < 4; ++c) {
            if (c < 3) {
                int chn = w * 64 + 16 * (c + 1) + 4 * q;
                #pragma unroll
                for (int r = 0; r < 4; ++r) {
                    pv1[r] = *(const ushort4*)(Pb + oP[r] + chn);
                    qv1[r] = *(const ushort4*)(Qb + oQ[r] + chn);
                }
            }
            int ch = w * 64 + 16 * c + 4 * q;
            #pragma unroll
            for (int r = 0; r < 4; ++r) {
                union { ushort4 v; ushort_t s[4]; } pu, qu;
                pu.v = pv0[r]; qu.v = qv0[r];
                ushort4 u;
                u.x = f2bf(elu_f(acc[r][c][0] + bf2f(pu.s[0]) + bf2f(qu.s[0])));
                u.y = f2bf(elu_f(acc[r][c][1] + bf2f(pu.s[1]) + bf2f(qu.s[1])));
                u.z = f2bf(elu_f(acc[r][c][2] + bf2f(pu.s[2]) + bf2f(qu.s[2])));
                u.w = f2bf(elu_f(acc[r][c][3] + bf2f(pu.s[3]) + bf2f(qu.s[3])));
                *(ushort4*)&As[16 * r + ln15][ch] = u;
            }
            #pragma unroll
            for (int r = 0; r < 4; ++r) { pv0[r] = pv1[r]; qv0[r] = qv1[r]; }
        }
    }
    __syncthreads();

    // L2 GEMM: acc = hidden @ W4b
    #pragma unroll
    for (int r = 0; r < 4; ++r)
        #pragma unroll
        for (int c = 0; c < 4; ++c)
            acc[r][c][0] = acc[r][c][1] = acc[r][c][2] = acc[r][c][3] = 0.f;
    {
        bf16x8 wf0[4];
        #pragma unroll
        for (int c = 0; c < 4; ++c)
            wf0[c] = *(const bf16x8*)(WbT + wch[c] + klane);
        #pragma unroll
        for (int kc = 0; kc < 8; ++kc) {
            bf16x8 wf1[4];
            if (kc < 7) {
                #pragma unroll
                for (int c = 0; c < 4; ++c)
                    wf1[c] = *(const bf16x8*)(WbT + wch[c] + (kc + 1) * 32 + klane);
            }
            bf16x8 af[4];
            #pragma unroll
            for (int r = 0; r < 4; ++r)
                af[r] = *(const bf16x8*)&As[16 * r + ln15][kc * 32 + klane];
            #pragma unroll
            for (int r = 0; r < 4; ++r)
                #pragma unroll
                for (int c = 0; c < 4; ++c)
                    acc[r][c] = __builtin_amdgcn_mfma_f32_16x16x32_bf16(wf0[c], af[r], acc[r][c], 0, 0, 0);
            #pragma unroll
            for (int c = 0; c < 4; ++c) wf0[c] = wf1[c];
        }
    }
    __syncthreads();    // hidden reads done before park overwrite

    // x4 = ELU(acc + b2) -> As park
    #pragma unroll
    for (int c = 0; c < 4; ++c) {
        float4 bv = *(const float4*)&b2[w * 64 + 16 * c + 4 * q];
        #pragma unroll
        for (int r = 0; r < 4; ++r) {
            ushort4 u;
            u.x = f2bf(elu_f(acc[r][c][0] + bv.x));
            u.y = f2bf(elu_f(acc[r][c][1] + bv.y));
            u.z = f2bf(elu_f(acc[r][c][2] + bv.z));
            u.w = f2bf(elu_f(acc[r][c][3] + bv.w));
            *(ushort4*)&As[16 * r + ln15][w * 64 + 16 * c + 4 * q] = u;
        }
    }
    __syncthreads();

    // coalesced global write (in-place over X2 rows of this block)
    #pragma unroll
    for (int m = 0; m < 8; ++m) {
        int ch = tid + m * 256;
        int row = ch >> 5;
        int o = (ch & 31) * 8;
        *(uint4*)&Y[((size_t)(Rbase + row)) * 256 + o] = *(const uint4*)&As[row][o];
    }

    // BN-stats: 64 threads x 4 channels, ushort4 column scan -> bf16 partials
    if (tid < 64) {
        int c4 = tid * 4;
        float s[4] = {0.f, 0.f, 0.f, 0.f};
        float qq[4] = {0.f, 0.f, 0.f, 0.f};
        for (int r = 0; r < 64; ++r) {
            union { ushort4 v; ushort_t e[4]; } u;
            u.v = *(const ushort4*)&As[r][c4];
            #pragma unroll
            for (int g = 0; g < 4; ++g) {
                float v = bf2f(u.e[g]);
                s[g] += v;
                qq[g] = fmaf(v, v, qq[g]);
            }
        }
        size_t base = (size_t)blockIdx.x * 512;
        ushort4 us, uq;
        us.x = f2bf(s[0]);  us.y = f2bf(s[1]);  us.z = f2bf(s[2]);  us.w = f2bf(s[3]);
        uq.x = f2bf(qq[0]); uq.y = f2bf(qq[1]); uq.z = f2bf(qq[2]); uq.w = f2bf(qq[3]);
        *(ushort4*)&pstat[base + c4]       = us;
        *(ushort4*)&pstat[base + 256 + c4] = uq;
    }
}

// ---- reduce per-block partials -> stats (64 blocks: 64 atomics/address) ---
__global__ __launch_bounds__(256)
void reduce_stats(const ushort_t* __restrict__ pstat, float* __restrict__ stats)
{
    int c = threadIdx.x;
    float s = 0.f, q = 0.f;
    for (int b = blockIdx.x; b < NBLK; b += 64) {
        size_t base = (size_t)b * 512;
        s += bf2f(pstat[base + c]);
        q += bf2f(pstat[base + 256 + c]);
    }
    atomicAdd(&stats[c], s);
    atomicAdd(&stats[256 + c], q);
}

// ---- fold BN + fc into Wfold[256][2], bfold[2] ----------------------------
__global__ __launch_bounds__(256)
void fold_kernel(const float* __restrict__ stats,
                 const float* __restrict__ gamma, const float* __restrict__ beta,
                 const float* __restrict__ fcW, const float* __restrict__ fcb,
                 float* __restrict__ fold)
{
    __shared__ float red0[256], red1[256];
    int c = threadIdx.x;
    float mean  = stats[c] * (1.f / M_BIG);
    float var   = stats[256 + c] * (1.f / M_BIG) - mean * mean;
    float inv   = rsqrtf(var + 1e-5f);
    float scale = inv * gamma[c];
    float sh    = beta[c] - mean * scale;
    float w0 = fcW[c * 2 + 0], w1 = fcW[c * 2 + 1];
    fold[c * 2 + 0] = scale * w0;
    fold[c * 2 + 1] = scale * w1;
    red0[c] = sh * w0;
    red1[c] = sh * w1;
    __syncthreads();
    for (int off = 128; off > 0; off >>= 1) {
        if (c < off) { red0[c] += red0[c + off]; red1[c] += red1[c + off]; }
        __syncthreads();
    }
    if (c == 0) {
        fold[512] = red0[0] + fcb[0];
        fold[513] = red1[0] + fcb[1];
    }
}

// ---- final: out[R][2] = x4_row . Wfold + bfold  (32 lanes per row, uint4) -
__global__ __launch_bounds__(256)
void final_kernel(const ushort_t* __restrict__ x4, const float* __restrict__ fold,
                  float* __restrict__ out)
{
    int tid  = threadIdx.x;
    int l32  = tid & 31;
    int g    = tid >> 5;          // 8 row-groups per block
    int R = blockIdx.x * 8 + g;
    int c0 = l32 * 8;
    union { uint4 qv; ushort_t s[8]; } u;
    u.qv = *(const uint4*)(x4 + (size_t)R * 256 + c0);
    float a0 = 0.f, a1 = 0.f;
    #pragma unroll
    for (int j = 0; j < 8; ++j) {
        float v = bf2f(u.s[j]);
        a0 = fmaf(v, fold[(c0 + j) * 2 + 0], a0);
        a1 = fmaf(v, fold[(c0 + j) * 2 + 1], a1);
    }
    #pragma unroll
    for (int off = 16; off > 0; off >>= 1) {
        a0 += __shfl_down(a0, off);
        a1 += __shfl_down(a1, off);
    }
    if (l32 == 0) {
        out[(size_t)R * 2 + 0] = a0 + fold[512];
        out[(size_t)R * 2 + 1] = a1 + fold[513];
    }
}

extern "C" void kernel_launch(void* const* d_in, const int* in_sizes, int n_in,
                              void* d_out, int out_size, void* d_ws, size_t ws_size,
                              hipStream_t stream)
{
    (void)in_sizes; (void)n_in; (void)out_size; (void)ws_size;

    const float* inputs = (const float*)d_in[0];
    const float* m1W1 = (const float*)d_in[3];
    const float* m1b1 = (const float*)d_in[4];
    const float* m1W2 = (const float*)d_in[5];
    const float* m1b2 = (const float*)d_in[6];
    const float* m2W1 = (const float*)d_in[7];
    const float* m2b1 = (const float*)d_in[8];
    const float* m2W2 = (const float*)d_in[9];
    const float* m2b2 = (const float*)d_in[10];
    const float* m3W1 = (const float*)d_in[11];
    const float* m3b1 = (const float*)d_in[12];
    const float* m3W2 = (const float*)d_in[13];
    const float* m3b2 = (const float*)d_in[14];
    const float* m4W1 = (const float*)d_in[15];
    const float* m4b1 = (const float*)d_in[16];
    const float* m4W2 = (const float*)d_in[17];
    const float* m4b2 = (const float*)d_in[18];
    const float* gamma = (const float*)d_in[19];
    const float* beta  = (const float*)d_in[20];
    const float* fcW   = (const float*)d_in[21];
    const float* fcb   = (const float*)d_in[22];
    float* out = (float*)d_out;

    // ---- workspace layout (~173 MB) ----
    char* ws = (char*)d_ws;
    const size_t BIGB  = (size_t)M_BIG * 256 * 2;     // 162,201,600
    const size_t SMALL = (size_t)M_SMALL * 256 * 4;   // 3,276,800 (fp32 small)
    const size_t HB    = (size_t)M_SMALL * 256 * 2;   // 1,638,400 (bf16 small)
    ushort_t* bigX     = (ushort_t*)ws;                       // x2 then x4
    float*    hsm      = (float*)(ws + BIGB);                 // h1 then h3 (fp32)
    float*    incoming = (float*)(ws + BIGB + SMALL);
    // pstat (4950*512 bf16 = 5.07 MB) overlaps hsm+incoming (dead by then)
    ushort_t* pstat    = (ushort_t*)(ws + BIGB);
    ushort_t* Pbuf     = (ushort_t*)(ws + BIGB + 2 * SMALL);
    ushort_t* Qbuf     = (ushort_t*)(ws + BIGB + 2 * SMALL + HB);
    float*    stats    = (float*)(ws + BIGB + 2 * SMALL + 2 * HB);
    float*    fold     = stats + 512;
    ushort_t* w2t      = (ushort_t*)(ws + BIGB + 2 * SMALL + 2 * HB + 8192);
    ushort_t* w4at     = w2t + 256 * 256;     // W4a3 (rows 512..767 of m4W1)
    ushort_t* w4bt     = w4at + 256 * 256;

    hipMemsetAsync(stats, 0, 2048, stream);
    hipMemsetAsync(incoming, 0, SMALL, stream);

    dim3 blk(256);
    wcvt3_kernel<<<48, blk, 0, stream>>>(m2W2, m4W1 + 512 * 256, m4W2, w2t, w4at, w4bt);
    // MLP1 -> h1 (fp32)
    fused_small<<<M_SMALL / 64, blk, 0, stream>>>(inputs, 200, 1.f, m1W1, m1b1, m1W2, m1b2, hsm);
    // P2 = h1@W1a + b1, Q2 = h1@W1b
    pq_gemm<<<100, blk, 0, stream>>>(hsm, m2W1, m2W1 + 256 * 256, m2b1, Pbuf, Qbuf);
    // edge MLP2 -> x2 + e2n sums
    edge_mlp2<<<M_BIG / 64, blk, 0, stream>>>(Pbuf, Qbuf, w2t, m2b2, bigX, incoming);
    // MLP3 (incoming/9900) -> h3 (fp32)
    fused_small<<<M_SMALL / 64, blk, 0, stream>>>(incoming, 256, 1.f / 9900.f, m3W1, m3b1, m3W2, m3b2, hsm);
    // P4 = h3@W4a1 + b1, Q4 = h3@W4a2
    pq_gemm<<<100, blk, 0, stream>>>(hsm, m4W1, m4W1 + 256 * 256, m4b1, Pbuf, Qbuf);
    // edge MLP4 -> x4 (in-place) + per-block stats partials
    edge_mlp4<<<M_BIG / 64, blk, 0, stream>>>(Pbuf, Qbuf, bigX, w4at, w4bt, m4b2, bigX, pstat);
    // partials -> stats -> fold -> final
    reduce_stats<<<64, blk, 0, stream>>>(pstat, stats);
    fold_kernel<<<1, blk, 0, stream>>>(stats, gamma, beta, fcW, fcb, fold);
    final_kernel<<<M_BIG / 8, blk, 0, stream>>>(bigX, fold, out);
}

// Round 10
// 813.953 us; speedup vs baseline: 1.0617x; 1.0538x over previous
//
#include <hip/hip_runtime.h>
#include <math.h>

// ---------------------------------------------------------------------------
// MLPEncoder (NRI encoder) on MI355X — round 10: 128-row tiles (m92->m103
// ladder move). Each edge block = 128 rows, 4 waves, 8x4 acc tiles per wave:
// 32 MFMA per kc per wave vs 16 before -> W-fragment loads amortized 2x and
// prefetch now covered by MFMA issue. Rest of pipeline = R9.
// ---------------------------------------------------------------------------

typedef unsigned short ushort_t;
typedef __bf16 bf16x8 __attribute__((ext_vector_type(8)));
typedef float  f32x4  __attribute__((ext_vector_type(4)));

#define E_EDGES 9900
#define NNODE   100
#define HID     256
#define M_BIG   316800
#define M_SMALL 3200
#define NBLK2   (M_BIG / 128)   /* 2475 */

__device__ __forceinline__ float bf2f(ushort_t u) {
    union { unsigned int i; float f; } v; v.i = ((unsigned int)u) << 16; return v.f;
}
__device__ __forceinline__ ushort_t f2bf(float f) {
    union { float f; unsigned int i; } v; v.f = f;
    return (ushort_t)((v.i + 0x7fffu + ((v.i >> 16) & 1u)) >> 16);   // RNE
}
__device__ __forceinline__ float elu_f(float x) {
    return x > 0.f ? x : (__expf(x) - 1.f);
}

// ---- convert+transpose 3 [256,256] fp32 matrices -> bf16 WT[chan][256] ----
__global__ __launch_bounds__(256)
void wcvt3_kernel(const float* __restrict__ W0, const float* __restrict__ W1,
                  const float* __restrict__ W2,
                  ushort_t* __restrict__ T0, ushort_t* __restrict__ T1,
                  ushort_t* __restrict__ T2)
{
    int bid = blockIdx.x;
    const float* W; ushort_t* WT; int tile;
    if (bid < 16)      { W = W0; WT = T0; tile = bid; }
    else if (bid < 32) { W = W1; WT = T1; tile = bid - 16; }
    else               { W = W2; WT = T2; tile = bid - 32; }
    int k0 = (tile >> 2) * 64, c0 = (tile & 3) * 64;
    __shared__ float S[64][65];
    int t = threadIdx.x;
    #pragma unroll
    for (int i = 0; i < 16; ++i) {
        int idx = t + i * 256;
        S[idx >> 6][idx & 63] = W[(size_t)(k0 + (idx >> 6)) * 256 + c0 + (idx & 63)];
    }
    __syncthreads();
    int col = t & 63;
    int kb  = (t >> 6) * 16;
    ushort_t* dst = WT + (size_t)(c0 + col) * 256 + k0 + kb;
    #pragma unroll
    for (int jj = 0; jj < 4; ++jj) {
        ushort4 u;
        u.x = f2bf(S[kb + 4 * jj + 0][col]);
        u.y = f2bf(S[kb + 4 * jj + 1][col]);
        u.z = f2bf(S[kb + 4 * jj + 2][col]);
        u.w = f2bf(S[kb + 4 * jj + 3][col]);
        *(ushort4*)(dst + 4 * jj) = u;
    }
}

// ---- fused small 2-layer fp32 MLP: X[3200,K0] -> ELU MLP -> fp32 [3200,256]
#define FMA_ROW(ri, xs) \
    acc[ri][0] = fmaf(xs, w.x, acc[ri][0]); \
    acc[ri][1] = fmaf(xs, w.y, acc[ri][1]); \
    acc[ri][2] = fmaf(xs, w.z, acc[ri][2]); \
    acc[ri][3] = fmaf(xs, w.w, acc[ri][3]);

__global__ __launch_bounds__(256, 2)
void fused_small(const float* __restrict__ X, int K0, float xscale,
                 const float* __restrict__ W1, const float* __restrict__ b1,
                 const float* __restrict__ W2, const float* __restrict__ b2,
                 float* __restrict__ Yf)
{
    __shared__ float Xs[32][68];
    __shared__ float Ws[32][256];
    __shared__ float Hs[64][257];
    const int tid = threadIdx.x;
    const int Rbase = blockIdx.x * 64;
    const int c0 = (tid & 63) * 4;
    const int r0 = (tid >> 6) * 16;
    const int r_st = tid & 63;
    const int kb = (tid >> 6) * 8;

    float acc[16][4];
    #pragma unroll
    for (int i = 0; i < 16; ++i)
        #pragma unroll
        for (int j = 0; j < 4; ++j) acc[i][j] = 0.f;

    const int nch = (K0 + 31) >> 5;
    for (int kc = 0; kc < nch; ++kc) {
        if (kc) __syncthreads();
        {
            int kg = kc * 32 + kb;
            const float* p = X + (size_t)(Rbase + r_st) * K0 + kg;
            float v[8];
            if (kg + 8 <= K0) {
                float4 a = *(const float4*)p;
                float4 b = *(const float4*)(p + 4);
                v[0]=a.x; v[1]=a.y; v[2]=a.z; v[3]=a.w;
                v[4]=b.x; v[5]=b.y; v[6]=b.z; v[7]=b.w;
            } else {
                #pragma unroll
                for (int j = 0; j < 8; ++j) v[j] = (kg + j < K0) ? p[j] : 0.f;
            }
            #pragma unroll
            for (int j = 0; j < 8; ++j) Xs[kb + j][r_st] = v[j];
        }
        #pragma unroll
        for (int m = 0; m < 8; ++m) {
            int f  = tid + m * 256;
            int kk = f >> 6;
            int cc = (f & 63) * 4;
            int kg = kc * 32 + kk;
            float4 w = (kg < K0) ? *(const float4*)&W1[(size_t)kg * 256 + cc]
                                 : make_float4(0.f, 0.f, 0.f, 0.f);
            *(float4*)&Ws[kk][cc] = w;
        }
        __syncthreads();
        #pragma unroll 8
        for (int kk = 0; kk < 32; ++kk) {
            float4 w = *(const float4*)&Ws[kk][c0];
            #pragma unroll
            for (int i = 0; i < 4; ++i) {
                float4 x = *(const float4*)&Xs[kk][r0 + 4 * i];
                FMA_ROW(4 * i + 0, x.x)
                FMA_ROW(4 * i + 1, x.y)
                FMA_ROW(4 * i + 2, x.z)
                FMA_ROW(4 * i + 3, x.w)
            }
        }
    }
    {
        float4 bv = *(const float4*)&b1[c0];
        #pragma unroll
        for (int i = 0; i < 16; ++i) {
            Hs[r0 + i][c0 + 0] = elu_f(acc[i][0] * xscale + bv.x);
            Hs[r0 + i][c0 + 1] = elu_f(acc[i][1] * xscale + bv.y);
            Hs[r0 + i][c0 + 2] = elu_f(acc[i][2] * xscale + bv.z);
            Hs[r0 + i][c0 + 3] = elu_f(acc[i][3] * xscale + bv.w);
        }
    }
    #pragma unroll
    for (int i = 0; i < 16; ++i)
        #pragma unroll
        for (int j = 0; j < 4; ++j) acc[i][j] = 0.f;
    for (int kc = 0; kc < 8; ++kc) {
        __syncthreads();
        {
            #pragma unroll
            for (int j = 0; j < 8; ++j) Xs[kb + j][r_st] = Hs[r_st][kc * 32 + kb + j];
        }
        #pragma unroll
        for (int m = 0; m < 8; ++m) {
            int f  = tid + m * 256;
            int kk = f >> 6;
            int cc = (f & 63) * 4;
            *(float4*)&Ws[kk][cc] = *(const float4*)&W2[(size_t)(kc * 32 + kk) * 256 + cc];
        }
        __syncthreads();
        #pragma unroll 8
        for (int kk = 0; kk < 32; ++kk) {
            float4 w = *(const float4*)&Ws[kk][c0];
            #pragma unroll
            for (int i = 0; i < 4; ++i) {
                float4 x = *(const float4*)&Xs[kk][r0 + 4 * i];
                FMA_ROW(4 * i + 0, x.x)
                FMA_ROW(4 * i + 1, x.y)
                FMA_ROW(4 * i + 2, x.z)
                FMA_ROW(4 * i + 3, x.w)
            }
        }
    }
    {
        float4 bv = *(const float4*)&b2[c0];
        #pragma unroll
        for (int i = 0; i < 16; ++i) {
            int R = Rbase + r0 + i;
            *(float4*)&Yf[(size_t)R * 256 + c0] = make_float4(
                elu_f(acc[i][0] + bv.x), elu_f(acc[i][1] + bv.y),
                elu_f(acc[i][2] + bv.z), elu_f(acc[i][3] + bv.w));
        }
    }
}

// ---- P/Q partial GEMMs: P = X@Wa + biasA (no act), Q = X@Wb (bf16 out) ----
__global__ __launch_bounds__(256, 2)
void pq_gemm(const float* __restrict__ X,
             const float* __restrict__ Wa, const float* __restrict__ Wb_,
             const float* __restrict__ biasA,
             ushort_t* __restrict__ Yp, ushort_t* __restrict__ Yq)
{
    const int bid = blockIdx.x;
    const float* W; const float* bias; ushort_t* Y; int Rbase;
    if (bid < 50) { W = Wa;  bias = biasA;  Y = Yp; Rbase = bid * 64; }
    else          { W = Wb_; bias = nullptr; Y = Yq; Rbase = (bid - 50) * 64; }

    __shared__ float Xs[32][68];
    __shared__ float Ws[32][256];
    const int tid = threadIdx.x;
    const int c0 = (tid & 63) * 4;
    const int r0 = (tid >> 6) * 16;
    const int r_st = tid & 63;
    const int kb = (tid >> 6) * 8;

    float acc[16][4];
    #pragma unroll
    for (int i = 0; i < 16; ++i)
        #pragma unroll
        for (int j = 0; j < 4; ++j) acc[i][j] = 0.f;

    for (int kc = 0; kc < 8; ++kc) {
        if (kc) __syncthreads();
        {
            const float* p = X + (size_t)(Rbase + r_st) * 256 + kc * 32 + kb;
            float4 a = *(const float4*)p;
            float4 b = *(const float4*)(p + 4);
            Xs[kb + 0][r_st] = a.x; Xs[kb + 1][r_st] = a.y;
            Xs[kb + 2][r_st] = a.z; Xs[kb + 3][r_st] = a.w;
            Xs[kb + 4][r_st] = b.x; Xs[kb + 5][r_st] = b.y;
            Xs[kb + 6][r_st] = b.z; Xs[kb + 7][r_st] = b.w;
        }
        #pragma unroll
        for (int m = 0; m < 8; ++m) {
            int f  = tid + m * 256;
            int kk = f >> 6;
            int cc = (f & 63) * 4;
            *(float4*)&Ws[kk][cc] = *(const float4*)&W[(size_t)(kc * 32 + kk) * 256 + cc];
        }
        __syncthreads();
        #pragma unroll 8
        for (int kk = 0; kk < 32; ++kk) {
            float4 w = *(const float4*)&Ws[kk][c0];
            #pragma unroll
            for (int i = 0; i < 4; ++i) {
                float4 x = *(const float4*)&Xs[kk][r0 + 4 * i];
                FMA_ROW(4 * i + 0, x.x)
                FMA_ROW(4 * i + 1, x.y)
                FMA_ROW(4 * i + 2, x.z)
                FMA_ROW(4 * i + 3, x.w)
            }
        }
    }
    float4 bv = bias ? *(const float4*)&bias[c0] : make_float4(0.f, 0.f, 0.f, 0.f);
    #pragma unroll
    for (int i = 0; i < 16; ++i) {
        int R = Rbase + r0 + i;
        ushort4 u;
        u.x = f2bf(acc[i][0] + bv.x);
        u.y = f2bf(acc[i][1] + bv.y);
        u.z = f2bf(acc[i][2] + bv.z);
        u.w = f2bf(acc[i][3] + bv.w);
        *(ushort4*)&Y[(size_t)R * 256 + c0] = u;
    }
}

// ---- edge kernel A (MLP2), 128-row tile ----------------------------------
__global__ __launch_bounds__(256, 2)
void edge_mlp2(const ushort_t* __restrict__ Pb, const ushort_t* __restrict__ Qb,
               const ushort_t* __restrict__ W2T,   // [chan][256] bf16
               const float* __restrict__ b2,
               ushort_t* __restrict__ Y, float* __restrict__ aux)
{
    __shared__ ushort_t As[128][264];   // hidden, then x2 park
    const int tid = threadIdx.x;
    const int w = tid >> 6;
    const int l = tid & 63;
    const int ln15 = l & 15;
    const int q = l >> 4;
    const int klane = 8 * q;
    const int Rbase = blockIdx.x * 128;

    // phase 1: hidden tile (two 64-row halves, batched loads)
    for (int h = 0; h < 2; ++h) {
        int row = (tid >> 2) + 64 * h;
        int R = Rbase + row;
        int b = R / E_EDGES;
        int e = R - b * E_EDGES;
        int i = e / 99;
        int k = e - 99 * i;
        int j = k + (k >= i ? 1 : 0);
        const ushort_t* prow = Pb + (size_t)(b * NNODE + j) * HID;
        const ushort_t* qrow = Qb + (size_t)(b * NNODE + i) * HID;
        int off = (tid & 3) * 8;
        uint4 pv[8], qv[8];
        #pragma unroll
        for (int u = 0; u < 8; ++u) {
            int o = off + u * 32;
            pv[u] = *(const uint4*)(prow + o);
            qv[u] = *(const uint4*)(qrow + o);
        }
        #pragma unroll
        for (int u = 0; u < 8; ++u) {
            int o = off + u * 32;
            union { uint4 v; ushort_t s[8]; } pu, qu, hu;
            pu.v = pv[u]; qu.v = qv[u];
            #pragma unroll
            for (int x = 0; x < 8; ++x)
                hu.s[x] = f2bf(elu_f(bf2f(pu.s[x]) + bf2f(qu.s[x])));
            *(uint4*)&As[row][o] = hu.v;
        }
    }
    __syncthreads();

    // GEMM: 8 row-tiles x 4 col-tiles per wave
    f32x4 acc[8][4];
    #pragma unroll
    for (int r = 0; r < 8; ++r)
        #pragma unroll
        for (int c = 0; c < 4; ++c)
            acc[r][c][0] = acc[r][c][1] = acc[r][c][2] = acc[r][c][3] = 0.f;
    int wch[4];
    #pragma unroll
    for (int c = 0; c < 4; ++c) wch[c] = (w * 64 + 16 * c + ln15) * 256;
    {
        bf16x8 wf0[4];
        #pragma unroll
        for (int c = 0; c < 4; ++c)
            wf0[c] = *(const bf16x8*)(W2T + wch[c] + klane);
        #pragma unroll
        for (int kc = 0; kc < 8; ++kc) {
            bf16x8 wf1[4];
            if (kc < 7) {
                #pragma unroll
                for (int c = 0; c < 4; ++c)
                    wf1[c] = *(const bf16x8*)(W2T + wch[c] + (kc + 1) * 32 + klane);
            }
            bf16x8 af[8];
            #pragma unroll
            for (int r = 0; r < 8; ++r)
                af[r] = *(const bf16x8*)&As[16 * r + ln15][kc * 32 + klane];
            #pragma unroll
            for (int r = 0; r < 8; ++r)
                #pragma unroll
                for (int c = 0; c < 4; ++c)
                    acc[r][c] = __builtin_amdgcn_mfma_f32_16x16x32_bf16(wf0[c], af[r], acc[r][c], 0, 0, 0);
            #pragma unroll
            for (int c = 0; c < 4; ++c) wf0[c] = wf1[c];
        }
    }
    __syncthreads();    // hidden reads done

    // park x2 = ELU(acc + b2)
    #pragma unroll
    for (int c = 0; c < 4; ++c) {
        float4 bv = *(const float4*)&b2[w * 64 + 16 * c + 4 * q];
        #pragma unroll
        for (int r = 0; r < 8; ++r) {
            ushort4 u;
            u.x = f2bf(elu_f(acc[r][c][0] + bv.x));
            u.y = f2bf(elu_f(acc[r][c][1] + bv.y));
            u.z = f2bf(elu_f(acc[r][c][2] + bv.z));
            u.w = f2bf(elu_f(acc[r][c][3] + bv.w));
            *(ushort4*)&As[16 * r + ln15][w * 64 + 16 * c + 4 * q] = u;
        }
    }
    __syncthreads();

    // coalesced global write (128 rows)
    #pragma unroll
    for (int m = 0; m < 16; ++m) {
        int ch = tid + m * 256;
        int row = ch >> 5;
        int o = (ch & 31) * 8;
        *(uint4*)&Y[((size_t)(Rbase + row)) * 256 + o] = *(const uint4*)&As[row][o];
    }

    // e2n epilogue: 64 threads x 4 channels over 128 rows
    if (tid < 64) {
        int c4 = tid * 4;
        int bn = Rbase / 99;
        int left = 99 - (Rbase - bn * 99);
        float s[4] = {0.f, 0.f, 0.f, 0.f};
        for (int r = 0; r < 128; ++r) {
            union { ushort4 v; ushort_t e[4]; } u;
            u.v = *(const ushort4*)&As[r][c4];
            #pragma unroll
            for (int g = 0; g < 4; ++g) s[g] += bf2f(u.e[g]);
            if (--left == 0) {
                #pragma unroll
                for (int g = 0; g < 4; ++g) {
                    atomicAdd(&aux[(size_t)bn * 256 + c4 + g], s[g]);
                    s[g] = 0.f;
                }
                ++bn; left = 99;
            }
        }
        #pragma unroll
        for (int g = 0; g < 4; ++g)
            atomicAdd(&aux[(size_t)bn * 256 + c4 + g], s[g]);
    }
}

// ---- edge kernel B (MLP4), 128-row tile ----------------------------------
__global__ __launch_bounds__(256, 2)
void edge_mlp4(const ushort_t* __restrict__ Pb, const ushort_t* __restrict__ Qb,
               const ushort_t* __restrict__ X2,
               const ushort_t* __restrict__ WaT,   // [chan][256] bf16
               const ushort_t* __restrict__ WbT,   // [chan][256] bf16
               const float* __restrict__ b2,
               ushort_t* __restrict__ Y, ushort_t* __restrict__ pstat)
{
    __shared__ ushort_t As[128][264];   // x2 tile -> hidden -> x4 park
    const int tid = threadIdx.x;
    const int w = tid >> 6;
    const int l = tid & 63;
    const int ln15 = l & 15;
    const int q = l >> 4;
    const int klane = 8 * q;
    const int Rbase = blockIdx.x * 128;

    // phase 0: stage x2 tile (two halves, batched)
    #pragma unroll
    for (int h = 0; h < 2; ++h) {
        int row = (tid >> 2) + 64 * h;
        const ushort_t* xrow = X2 + (size_t)(Rbase + row) * 256;
        int off = (tid & 3) * 8;
        uint4 xv[8];
        #pragma unroll
        for (int u = 0; u < 8; ++u) xv[u] = *(const uint4*)(xrow + off + u * 32);
        #pragma unroll
        for (int u = 0; u < 8; ++u) *(uint4*)&As[row][off + u * 32] = xv[u];
    }

    // per-lane P/Q row offsets for 8 row-tiles
    int oP[8], oQ[8];
    #pragma unroll
    for (int r = 0; r < 8; ++r) {
        int R = Rbase + 16 * r + ln15;
        int b = R / E_EDGES;
        int e = R - b * E_EDGES;
        int i = e / 99;
        int k = e - 99 * i;
        int j = k + (k >= i ? 1 : 0);
        oP[r] = (b * NNODE + j) * HID;
        oQ[r] = (b * NNODE + i) * HID;
    }
    __syncthreads();

    f32x4 acc[8][4];
    int wch[4];
    #pragma unroll
    for (int c = 0; c < 4; ++c) wch[c] = (w * 64 + 16 * c + ln15) * 256;

    // L1 GEMM: acc = x2tile @ W4a3
    #pragma unroll
    for (int r = 0; r < 8; ++r)
        #pragma unroll
        for (int c = 0; c < 4; ++c)
            acc[r][c][0] = acc[r][c][1] = acc[r][c][2] = acc[r][c][3] = 0.f;
    {
        bf16x8 wf0[4];
        #pragma unroll
        for (int c = 0; c < 4; ++c)
            wf0[c] = *(const bf16x8*)(WaT + wch[c] + klane);
        #pragma unroll
        for (int kc = 0; kc < 8; ++kc) {
            bf16x8 wf1[4];
            if (kc < 7) {
                #pragma unroll
                for (int c = 0; c < 4; ++c)
                    wf1[c] = *(const bf16x8*)(WaT + wch[c] + (kc + 1) * 32 + klane);
            }
            bf16x8 af[8];
            #pragma unroll
            for (int r = 0; r < 8; ++r)
                af[r] = *(const bf16x8*)&As[16 * r + ln15][kc * 32 + klane];
            #pragma unroll
            for (int r = 0; r < 8; ++r)
                #pragma unroll
                for (int c = 0; c < 4; ++c)
                    acc[r][c] = __builtin_amdgcn_mfma_f32_16x16x32_bf16(wf0[c], af[r], acc[r][c], 0, 0, 0);
            #pragma unroll
            for (int c = 0; c < 4; ++c) wf0[c] = wf1[c];
        }
    }
    __syncthreads();    // x2 tile reads done

    // hidden = ELU(acc + P[j] + Q[i]) -> As  (P/Q batched per column-tile)
    #pragma unroll
    for (int c = 0; c < 4; ++c) {
        int ch = w * 64 + 16 * c + 4 * q;
        ushort4 pv[8], qv[8];
        #pragma unroll
        for (int r = 0; r < 8; ++r) {
            pv[r] = *(const ushort4*)(Pb + oP[r] + ch);
            qv[r] = *(const ushort4*)(Qb + oQ[r] + ch);
        }
        #pragma unroll
        for (int r = 0; r < 8; ++r) {
            union { ushort4 v; ushort_t s[4]; } pu, qu;
            pu.v = pv[r]; qu.v = qv[r];
            ushort4 u;
            u.x = f2bf(elu_f(acc[r][c][0] + bf2f(pu.s[0]) + bf2f(qu.s[0])));
            u.y = f2bf(elu_f(acc[r][c][1] + bf2f(pu.s[1]) + bf2f(qu.s[1])));
            u.z = f2bf(elu_f(acc[r][c][2] + bf2f(pu.s[2]) + bf2f(qu.s[2])));
            u.w = f2bf(elu_f(acc[r][c][3] + bf2f(pu.s[3]) + bf2f(qu.s[3])));
            *(ushort4*)&As[16 * r + ln15][ch] = u;
        }
    }
    __syncthreads();

    // L2 GEMM: acc = hidden @ W4b
    #pragma unroll
    for (int r = 0; r < 8; ++r)
        #pragma unroll
        for (int c = 0; c < 4; ++c)
            acc[r][c][0] = acc[r][c][1] = acc[r][c][2] = acc[r][c][3] = 0.f;
    {
        bf16x8 wf0[4];
        #pragma unroll
        for (int c = 0; c < 4; ++c)
            wf0[c] = *(const bf16x8*)(WbT + wch[c] + klane);
        #pragma unroll
        for (int kc = 0; kc < 8; ++kc) {
            bf16x8 wf1[4];
            if (kc < 7) {
                #pragma unroll
                for (int c = 0; c < 4; ++c)
                    wf1[c] = *(const bf16x8*)(WbT + wch[c] + (kc + 1) * 32 + klane);
            }
            bf16x8 af[8];
            #pragma unroll
            for (int r = 0; r < 8; ++r)
                af[r] = *(const bf16x8*)&As[16 * r + ln15][kc * 32 + klane];
            #pragma unroll
            for (int r = 0; r < 8; ++r)
                #pragma unroll
                for (int c = 0; c < 4; ++c)
                    acc[r][c] = __builtin_amdgcn_mfma_f32_16x16x32_bf16(wf0[c], af[r], acc[r][c], 0, 0, 0);
            #pragma unroll
            for (int c = 0; c < 4; ++c) wf0[c] = wf1[c];
        }
    }
    __syncthreads();    // hidden reads done before park overwrite

    // x4 = ELU(acc + b2) -> As park
    #pragma unroll
    for (int c = 0; c < 4; ++c) {
        float4 bv = *(const float4*)&b2[w * 64 + 16 * c + 4 * q];
        #pragma unroll
        for (int r = 0; r < 8; ++r) {
            ushort4 u;
            u.x = f2bf(elu_f(acc[r][c][0] + bv.x));
            u.y = f2bf(elu_f(acc[r][c][1] + bv.y));
            u.z = f2bf(elu_f(acc[r][c][2] + bv.z));
            u.w = f2bf(elu_f(acc[r][c][3] + bv.w));
            *(ushort4*)&As[16 * r + ln15][w * 64 + 16 * c + 4 * q] = u;
        }
    }
    __syncthreads();

    // coalesced global write (in-place over X2 rows of this block)
    #pragma unroll
    for (int m = 0; m < 16; ++m) {
        int ch = tid + m * 256;
        int row = ch >> 5;
        int o = (ch & 31) * 8;
        *(uint4*)&Y[((size_t)(Rbase + row)) * 256 + o] = *(const uint4*)&As[row][o];
    }

    // BN-stats: 64 threads x 4 channels over 128 rows -> bf16 partials
    if (tid < 64) {
        int c4 = tid * 4;
        float s[4] = {0.f, 0.f, 0.f, 0.f};
        float qq[4] = {0.f, 0.f, 0.f, 0.f};
        for (int r = 0; r < 128; ++r) {
            union { ushort4 v; ushort_t e[4]; } u;
            u.v = *(const ushort4*)&As[r][c4];
            #pragma unroll
            for (int g = 0; g < 4; ++g) {
                float v = bf2f(u.e[g]);
                s[g] += v;
                qq[g] = fmaf(v, v, qq[g]);
            }
        }
        size_t base = (size_t)blockIdx.x * 512;
        ushort4 us, uq;
        us.x = f2bf(s[0]);  us.y = f2bf(s[1]);  us.z = f2bf(s[2]);  us.w = f2bf(s[3]);
        uq.x = f2bf(qq[0]); uq.y = f2bf(qq[1]); uq.z = f2bf(qq[2]); uq.w = f2bf(qq[3]);
        *(ushort4*)&pstat[base + c4]       = us;
        *(ushort4*)&pstat[base + 256 + c4] = uq;
    }
}

// ---- reduce per-block partials -> stats -----------------------------------
__global__ __launch_bounds__(256)
void reduce_stats(const ushort_t* __restrict__ pstat, float* __restrict__ stats)
{
    int c = threadIdx.x;
    float s = 0.f, q = 0.f;
    for (int b = blockIdx.x; b < NBLK2; b += 64) {
        size_t base = (size_t)b * 512;
        s += bf2f(pstat[base + c]);
        q += bf2f(pstat[base + 256 + c]);
    }
    atomicAdd(&stats[c], s);
    atomicAdd(&stats[256 + c], q);
}

// ---- fold BN + fc into Wfold[256][2], bfold[2] ----------------------------
__global__ __launch_bounds__(256)
void fold_kernel(const float* __restrict__ stats,
                 const float* __restrict__ gamma, const float* __restrict__ beta,
                 const float* __restrict__ fcW, const float* __restrict__ fcb,
                 float* __restrict__ fold)
{
    __shared__ float red0[256], red1[256];
    int c = threadIdx.x;
    float mean  = stats[c] * (1.f / M_BIG);
    float var   = stats[256 + c] * (1.f / M_BIG) - mean * mean;
    float inv   = rsqrtf(var + 1e-5f);
    float scale = inv * gamma[c];
    float sh    = beta[c] - mean * scale;
    float w0 = fcW[c * 2 + 0], w1 = fcW[c * 2 + 1];
    fold[c * 2 + 0] = scale * w0;
    fold[c * 2 + 1] = scale * w1;
    red0[c] = sh * w0;
    red1[c] = sh * w1;
    __syncthreads();
    for (int off = 128; off > 0; off >>= 1) {
        if (c < off) { red0[c] += red0[c + off]; red1[c] += red1[c + off]; }
        __syncthreads();
    }
    if (c == 0) {
        fold[512] = red0[0] + fcb[0];
        fold[513] = red1[0] + fcb[1];
    }
}

// ---- final: out[R][2] = x4_row . Wfold + bfold  (32 lanes per row, uint4) -
__global__ __launch_bounds__(256)
void final_kernel(const ushort_t* __restrict__ x4, const float* __restrict__ fold,
                  float* __restrict__ out)
{
    int tid  = threadIdx.x;
    int l32  = tid & 31;
    int g    = tid >> 5;          // 8 row-groups per block
    int R = blockIdx.x * 8 + g;
    int c0 = l32 * 8;
    union { uint4 qv; ushort_t s[8]; } u;
    u.qv = *(const uint4*)(x4 + (size_t)R * 256 + c0);
    float a0 = 0.f, a1 = 0.f;
    #pragma unroll
    for (int j = 0; j < 8; ++j) {
        float v = bf2f(u.s[j]);
        a0 = fmaf(v, fold[(c0 + j) * 2 + 0], a0);
        a1 = fmaf(v, fold[(c0 + j) * 2 + 1], a1);
    }
    #pragma unroll
    for (int off = 16; off > 0; off >>= 1) {
        a0 += __shfl_down(a0, off);
        a1 += __shfl_down(a1, off);
    }
    if (l32 == 0) {
        out[(size_t)R * 2 + 0] = a0 + fold[512];
        out[(size_t)R * 2 + 1] = a1 + fold[513];
    }
}

extern "C" void kernel_launch(void* const* d_in, const int* in_sizes, int n_in,
                              void* d_out, int out_size, void* d_ws, size_t ws_size,
                              hipStream_t stream)
{
    (void)in_sizes; (void)n_in; (void)out_size; (void)ws_size;

    const float* inputs = (const float*)d_in[0];
    const float* m1W1 = (const float*)d_in[3];
    const float* m1b1 = (const float*)d_in[4];
    const float* m1W2 = (const float*)d_in[5];
    const float* m1b2 = (const float*)d_in[6];
    const float* m2W1 = (const float*)d_in[7];
    const float* m2b1 = (const float*)d_in[8];
    const float* m2W2 = (const float*)d_in[9];
    const float* m2b2 = (const float*)d_in[10];
    const float* m3W1 = (const float*)d_in[11];
    const float* m3b1 = (const float*)d_in[12];
    const float* m3W2 = (const float*)d_in[13];
    const float* m3b2 = (const float*)d_in[14];
    const float* m4W1 = (const float*)d_in[15];
    const float* m4b1 = (const float*)d_in[16];
    const float* m4W2 = (const float*)d_in[17];
    const float* m4b2 = (const float*)d_in[18];
    const float* gamma = (const float*)d_in[19];
    const float* beta  = (const float*)d_in[20];
    const float* fcW   = (const float*)d_in[21];
    const float* fcb   = (const float*)d_in[22];
    float* out = (float*)d_out;

    // ---- workspace layout (~173 MB) ----
    char* ws = (char*)d_ws;
    const size_t BIGB  = (size_t)M_BIG * 256 * 2;     // 162,201,600
    const size_t SMALL = (size_t)M_SMALL * 256 * 4;   // 3,276,800 (fp32 small)
    const size_t HB    = (size_t)M_SMALL * 256 * 2;   // 1,638,400 (bf16 small)
    ushort_t* bigX     = (ushort_t*)ws;                       // x2 then x4
    float*    hsm      = (float*)(ws + BIGB);                 // h1 then h3 (fp32)
    float*    incoming = (float*)(ws + BIGB + SMALL);
    // pstat (2475*512 bf16 = 2.5 MB) overlaps hsm (dead by then)
    ushort_t* pstat    = (ushort_t*)(ws + BIGB);
    ushort_t* Pbuf     = (ushort_t*)(ws + BIGB + 2 * SMALL);
    ushort_t* Qbuf     = (ushort_t*)(ws + BIGB + 2 * SMALL + HB);
    float*    stats    = (float*)(ws + BIGB + 2 * SMALL + 2 * HB);
    float*    fold     = stats + 512;
    ushort_t* w2t      = (ushort_t*)(ws + BIGB + 2 * SMALL + 2 * HB + 8192);
    ushort_t* w4at     = w2t + 256 * 256;     // W4a3 (rows 512..767 of m4W1)
    ushort_t* w4bt     = w4at + 256 * 256;

    hipMemsetAsync(stats, 0, 2048, stream);
    hipMemsetAsync(incoming, 0, SMALL, stream);

    dim3 blk(256);
    wcvt3_kernel<<<48, blk, 0, stream>>>(m2W2, m4W1 + 512 * 256, m4W2, w2t, w4at, w4bt);
    // MLP1 -> h1 (fp32)
    fused_small<<<M_SMALL / 64, blk, 0, stream>>>(inputs, 200, 1.f, m1W1, m1b1, m1W2, m1b2, hsm);
    // P2 = h1@W1a + b1, Q2 = h1@W1b
    pq_gemm<<<100, blk, 0, stream>>>(hsm, m2W1, m2W1 + 256 * 256, m2b1, Pbuf, Qbuf);
    // edge MLP2 (128-row tiles) -> x2 + e2n sums
    edge_mlp2<<<NBLK2, blk, 0, stream>>>(Pbuf, Qbuf, w2t, m2b2, bigX, incoming);
    // MLP3 (incoming/9900) -> h3 (fp32)
    fused_small<<<M_SMALL / 64, blk, 0, stream>>>(incoming, 256, 1.f / 9900.f, m3W1, m3b1, m3W2, m3b2, hsm);
    // P4 = h3@W4a1 + b1, Q4 = h3@W4a2
    pq_gemm<<<100, blk, 0, stream>>>(hsm, m4W1, m4W1 + 256 * 256, m4b1, Pbuf, Qbuf);
    // edge MLP4 (128-row tiles) -> x4 (in-place) + per-block stats partials
    edge_mlp4<<<NBLK2, blk, 0, stream>>>(Pbuf, Qbuf, bigX, w4at, w4bt, m4b2, bigX, pstat);
    // partials -> stats -> fold -> final
    reduce_stats<<<64, blk, 0, stream>>>(pstat, stats);
    fold_kernel<<<1, blk, 0, stream>>>(stats, gamma, beta, fcW, fcb, fold);
    final_kernel<<<M_BIG / 8, blk, 0, stream>>>(bigX, fold, out);
}

// Round 11
// 518.718 us; speedup vs baseline: 1.6660x; 1.5692x over previous
//
#include <hip/hip_runtime.h>
#include <math.h>

// ---------------------------------------------------------------------------
// MLPEncoder (NRI encoder) on MI355X — round 11: MFMA-ify the small chain.
//   R10 edge kernels kept verbatim (stride-parameterized weights only).
//   fused_small/pq_gemm (fp32 vector, ~260 us chain) replaced by a generic
//   32-row x 256-col bf16-MFMA kernel small_mfma (grid 100-200).
//   wcvt_all converts all 8 weight matrices to chan-major bf16 WT once.
// ---------------------------------------------------------------------------

typedef unsigned short ushort_t;
typedef __bf16 bf16x8 __attribute__((ext_vector_type(8)));
typedef float  f32x4  __attribute__((ext_vector_type(4)));

#define E_EDGES 9900
#define NNODE   100
#define HID     256
#define M_BIG   316800
#define M_SMALL 3200
#define NBLK2   (M_BIG / 128)   /* 2475 */

__device__ __forceinline__ float bf2f(ushort_t u) {
    union { unsigned int i; float f; } v; v.i = ((unsigned int)u) << 16; return v.f;
}
__device__ __forceinline__ ushort_t f2bf(float f) {
    union { float f; unsigned int i; } v; v.f = f;
    return (ushort_t)((v.i + 0x7fffu + ((v.i >> 16) & 1u)) >> 16);   // RNE
}
__device__ __forceinline__ float elu_f(float x) {
    return x > 0.f ? x : (__expf(x) - 1.f);
}

// ---- convert all weights to chan-major bf16 WT[col][K] --------------------
// blocks: m1W1(K200->256):16  m1W2:16  m2W1(512):32  m2W2:16
//         m3W1:16  m3W2:16  m4W1(768):48  m4W2:16   = 176
__global__ __launch_bounds__(256)
void wcvt_all(const float* __restrict__ s0, const float* __restrict__ s1,
              const float* __restrict__ s2, const float* __restrict__ s3,
              const float* __restrict__ s4, const float* __restrict__ s5,
              const float* __restrict__ s6, const float* __restrict__ s7,
              ushort_t* d0, ushort_t* d1, ushort_t* d2, ushort_t* d3,
              ushort_t* d4, ushort_t* d5, ushort_t* d6, ushort_t* d7)
{
    int bid = blockIdx.x;
    const float* S; ushort_t* D; int Kd, Kr, t;
    if      (bid < 16)  { S = s0; D = d0; Kd = 256; Kr = 200; t = bid; }
    else if (bid < 32)  { S = s1; D = d1; Kd = 256; Kr = 256; t = bid - 16; }
    else if (bid < 64)  { S = s2; D = d2; Kd = 512; Kr = 512; t = bid - 32; }
    else if (bid < 80)  { S = s3; D = d3; Kd = 256; Kr = 256; t = bid - 64; }
    else if (bid < 96)  { S = s4; D = d4; Kd = 256; Kr = 256; t = bid - 80; }
    else if (bid < 112) { S = s5; D = d5; Kd = 256; Kr = 256; t = bid - 96; }
    else if (bid < 160) { S = s6; D = d6; Kd = 768; Kr = 768; t = bid - 112; }
    else                { S = s7; D = d7; Kd = 256; Kr = 256; t = bid - 160; }
    int k0 = (t >> 2) * 64, c0 = (t & 3) * 64;
    __shared__ float Sh[64][65];
    int tid = threadIdx.x;
    #pragma unroll
    for (int i = 0; i < 16; ++i) {
        int idx = tid + i * 256;
        int kk = idx >> 6, cc = idx & 63;
        Sh[kk][cc] = (k0 + kk < Kr) ? S[(size_t)(k0 + kk) * 256 + c0 + cc] : 0.f;
    }
    __syncthreads();
    int col = tid & 63;
    int kb  = (tid >> 6) * 16;
    ushort_t* dst = D + (size_t)(c0 + col) * Kd + k0 + kb;
    #pragma unroll
    for (int jj = 0; jj < 4; ++jj) {
        ushort4 u;
        u.x = f2bf(Sh[kb + 4 * jj + 0][col]);
        u.y = f2bf(Sh[kb + 4 * jj + 1][col]);
        u.z = f2bf(Sh[kb + 4 * jj + 2][col]);
        u.w = f2bf(Sh[kb + 4 * jj + 3][col]);
        *(ushort4*)(dst + 4 * jj) = u;
    }
}

// ---- generic small MFMA GEMM: Y[3200,256] = act(xscale*X@W + b), bf16 out -
// Block = 32 rows x 256 cols; dual weight-set (blocks >= nb1 use set b).
// XF32: X is fp32 with row stride Kreal (zero-padded to kcN*32 in staging).
template<int XF32>
__global__ __launch_bounds__(256, 2)
void small_mfma(const float* __restrict__ Xf, const ushort_t* __restrict__ Xb,
                int Kreal, int kcN, float xscale, int act, int nb1,
                const ushort_t* __restrict__ WTa, int wsa,
                const float* __restrict__ ba, ushort_t* __restrict__ Ya,
                const ushort_t* __restrict__ WTb, int wsb,
                const float* __restrict__ bb, ushort_t* __restrict__ Yb)
{
    __shared__ ushort_t Xs[32][264];
    int bid = blockIdx.x;
    const ushort_t* WT; int wstr; const float* bias; ushort_t* Y;
    if (bid < nb1) { WT = WTa; wstr = wsa; bias = ba; Y = Ya; }
    else           { bid -= nb1; WT = WTb; wstr = wsb; bias = bb; Y = Yb; }
    const int tid = threadIdx.x;
    const int w = tid >> 6;
    const int l = tid & 63;
    const int ln15 = l & 15;
    const int q = l >> 4;
    const int klane = 8 * q;
    const int Rbase = bid * 32;

    // stage X tile (32 rows x kcN*32 cols) as bf16
    {
        int row = tid >> 3, seg = tid & 7;
        if (seg < kcN) {
            ushort_t tmp[32];
            if (XF32) {
                const float* src = Xf + (size_t)(Rbase + row) * Kreal + seg * 32;
                #pragma unroll
                for (int u = 0; u < 32; ++u)
                    tmp[u] = (seg * 32 + u < Kreal) ? f2bf(src[u]) : (ushort_t)0;
            } else {
                const ushort_t* src = Xb + (size_t)(Rbase + row) * 256 + seg * 32;
                #pragma unroll
                for (int u = 0; u < 4; ++u)
                    *(uint4*)&tmp[u * 8] = *(const uint4*)(src + u * 8);
            }
            #pragma unroll
            for (int u = 0; u < 4; ++u)
                *(uint4*)&Xs[row][seg * 32 + u * 8] = *(uint4*)&tmp[u * 8];
        }
    }
    __syncthreads();

    f32x4 acc[2][4];
    #pragma unroll
    for (int r = 0; r < 2; ++r)
        #pragma unroll
        for (int c = 0; c < 4; ++c)
            acc[r][c][0] = acc[r][c][1] = acc[r][c][2] = acc[r][c][3] = 0.f;
    int wch[4];
    #pragma unroll
    for (int c = 0; c < 4; ++c) wch[c] = (w * 64 + 16 * c + ln15) * wstr;

    {
        bf16x8 wf0[4];
        #pragma unroll
        for (int c = 0; c < 4; ++c)
            wf0[c] = *(const bf16x8*)(WT + wch[c] + klane);
        for (int kc = 0; kc < kcN; ++kc) {
            bf16x8 wf1[4];
            if (kc + 1 < kcN) {
                #pragma unroll
                for (int c = 0; c < 4; ++c)
                    wf1[c] = *(const bf16x8*)(WT + wch[c] + (kc + 1) * 32 + klane);
            }
            bf16x8 af[2];
            #pragma unroll
            for (int r = 0; r < 2; ++r)
                af[r] = *(const bf16x8*)&Xs[16 * r + ln15][kc * 32 + klane];
            #pragma unroll
            for (int r = 0; r < 2; ++r)
                #pragma unroll
                for (int c = 0; c < 4; ++c)
                    acc[r][c] = __builtin_amdgcn_mfma_f32_16x16x32_bf16(wf0[c], af[r], acc[r][c], 0, 0, 0);
            #pragma unroll
            for (int c = 0; c < 4; ++c) wf0[c] = wf1[c];
        }
    }
    __syncthreads();    // Xs reads done

    // epilogue: o = act(xscale*acc + b) -> park -> coalesced write
    #pragma unroll
    for (int c = 0; c < 4; ++c) {
        float4 bv = bias ? *(const float4*)&bias[w * 64 + 16 * c + 4 * q]
                         : make_float4(0.f, 0.f, 0.f, 0.f);
        #pragma unroll
        for (int r = 0; r < 2; ++r) {
            float o0 = acc[r][c][0] * xscale + bv.x;
            float o1 = acc[r][c][1] * xscale + bv.y;
            float o2 = acc[r][c][2] * xscale + bv.z;
            float o3 = acc[r][c][3] * xscale + bv.w;
            if (act) { o0 = elu_f(o0); o1 = elu_f(o1); o2 = elu_f(o2); o3 = elu_f(o3); }
            ushort4 u;
            u.x = f2bf(o0); u.y = f2bf(o1); u.z = f2bf(o2); u.w = f2bf(o3);
            *(ushort4*)&Xs[16 * r + ln15][w * 64 + 16 * c + 4 * q] = u;
        }
    }
    __syncthreads();
    #pragma unroll
    for (int m = 0; m < 4; ++m) {
        int ch = tid + m * 256;
        int row = ch >> 5;
        int o = (ch & 31) * 8;
        *(uint4*)&Y[(size_t)(Rbase + row) * 256 + o] = *(const uint4*)&Xs[row][o];
    }
}

// ---- edge kernel A (MLP2), 128-row tile (R10, unchanged) ------------------
__global__ __launch_bounds__(256, 2)
void edge_mlp2(const ushort_t* __restrict__ Pb, const ushort_t* __restrict__ Qb,
               const ushort_t* __restrict__ W2T,   // [chan][256] bf16
               const float* __restrict__ b2,
               ushort_t* __restrict__ Y, float* __restrict__ aux)
{
    __shared__ ushort_t As[128][264];
    const int tid = threadIdx.x;
    const int w = tid >> 6;
    const int l = tid & 63;
    const int ln15 = l & 15;
    const int q = l >> 4;
    const int klane = 8 * q;
    const int Rbase = blockIdx.x * 128;

    for (int h = 0; h < 2; ++h) {
        int row = (tid >> 2) + 64 * h;
        int R = Rbase + row;
        int b = R / E_EDGES;
        int e = R - b * E_EDGES;
        int i = e / 99;
        int k = e - 99 * i;
        int j = k + (k >= i ? 1 : 0);
        const ushort_t* prow = Pb + (size_t)(b * NNODE + j) * HID;
        const ushort_t* qrow = Qb + (size_t)(b * NNODE + i) * HID;
        int off = (tid & 3) * 8;
        uint4 pv[8], qv[8];
        #pragma unroll
        for (int u = 0; u < 8; ++u) {
            int o = off + u * 32;
            pv[u] = *(const uint4*)(prow + o);
            qv[u] = *(const uint4*)(qrow + o);
        }
        #pragma unroll
        for (int u = 0; u < 8; ++u) {
            int o = off + u * 32;
            union { uint4 v; ushort_t s[8]; } pu, qu, hu;
            pu.v = pv[u]; qu.v = qv[u];
            #pragma unroll
            for (int x = 0; x < 8; ++x)
                hu.s[x] = f2bf(elu_f(bf2f(pu.s[x]) + bf2f(qu.s[x])));
            *(uint4*)&As[row][o] = hu.v;
        }
    }
    __syncthreads();

    f32x4 acc[8][4];
    #pragma unroll
    for (int r = 0; r < 8; ++r)
        #pragma unroll
        for (int c = 0; c < 4; ++c)
            acc[r][c][0] = acc[r][c][1] = acc[r][c][2] = acc[r][c][3] = 0.f;
    int wch[4];
    #pragma unroll
    for (int c = 0; c < 4; ++c) wch[c] = (w * 64 + 16 * c + ln15) * 256;
    {
        bf16x8 wf0[4];
        #pragma unroll
        for (int c = 0; c < 4; ++c)
            wf0[c] = *(const bf16x8*)(W2T + wch[c] + klane);
        #pragma unroll
        for (int kc = 0; kc < 8; ++kc) {
            bf16x8 wf1[4];
            if (kc < 7) {
                #pragma unroll
                for (int c = 0; c < 4; ++c)
                    wf1[c] = *(const bf16x8*)(W2T + wch[c] + (kc + 1) * 32 + klane);
            }
            bf16x8 af[8];
            #pragma unroll
            for (int r = 0; r < 8; ++r)
                af[r] = *(const bf16x8*)&As[16 * r + ln15][kc * 32 + klane];
            #pragma unroll
            for (int r = 0; r < 8; ++r)
                #pragma unroll
                for (int c = 0; c < 4; ++c)
                    acc[r][c] = __builtin_amdgcn_mfma_f32_16x16x32_bf16(wf0[c], af[r], acc[r][c], 0, 0, 0);
            #pragma unroll
            for (int c = 0; c < 4; ++c) wf0[c] = wf1[c];
        }
    }
    __syncthreads();

    #pragma unroll
    for (int c = 0; c < 4; ++c) {
        float4 bv = *(const float4*)&b2[w * 64 + 16 * c + 4 * q];
        #pragma unroll
        for (int r = 0; r < 8; ++r) {
            ushort4 u;
            u.x = f2bf(elu_f(acc[r][c][0] + bv.x));
            u.y = f2bf(elu_f(acc[r][c][1] + bv.y));
            u.z = f2bf(elu_f(acc[r][c][2] + bv.z));
            u.w = f2bf(elu_f(acc[r][c][3] + bv.w));
            *(ushort4*)&As[16 * r + ln15][w * 64 + 16 * c + 4 * q] = u;
        }
    }
    __syncthreads();

    #pragma unroll
    for (int m = 0; m < 16; ++m) {
        int ch = tid + m * 256;
        int row = ch >> 5;
        int o = (ch & 31) * 8;
        *(uint4*)&Y[((size_t)(Rbase + row)) * 256 + o] = *(const uint4*)&As[row][o];
    }

    if (tid < 64) {
        int c4 = tid * 4;
        int bn = Rbase / 99;
        int left = 99 - (Rbase - bn * 99);
        float s[4] = {0.f, 0.f, 0.f, 0.f};
        for (int r = 0; r < 128; ++r) {
            union { ushort4 v; ushort_t e[4]; } u;
            u.v = *(const ushort4*)&As[r][c4];
            #pragma unroll
            for (int g = 0; g < 4; ++g) s[g] += bf2f(u.e[g]);
            if (--left == 0) {
                #pragma unroll
                for (int g = 0; g < 4; ++g) {
                    atomicAdd(&aux[(size_t)bn * 256 + c4 + g], s[g]);
                    s[g] = 0.f;
                }
                ++bn; left = 99;
            }
        }
        #pragma unroll
        for (int g = 0; g < 4; ++g)
            atomicAdd(&aux[(size_t)bn * 256 + c4 + g], s[g]);
    }
}

// ---- edge kernel B (MLP4), 128-row tile (R10 + weight strides) ------------
__global__ __launch_bounds__(256, 2)
void edge_mlp4(const ushort_t* __restrict__ Pb, const ushort_t* __restrict__ Qb,
               const ushort_t* __restrict__ X2,
               const ushort_t* __restrict__ WaT, int wsA,
               const ushort_t* __restrict__ WbT, int wsB,
               const float* __restrict__ b2,
               ushort_t* __restrict__ Y, ushort_t* __restrict__ pstat)
{
    __shared__ ushort_t As[128][264];
    const int tid = threadIdx.x;
    const int w = tid >> 6;
    const int l = tid & 63;
    const int ln15 = l & 15;
    const int q = l >> 4;
    const int klane = 8 * q;
    const int Rbase = blockIdx.x * 128;

    #pragma unroll
    for (int h = 0; h < 2; ++h) {
        int row = (tid >> 2) + 64 * h;
        const ushort_t* xrow = X2 + (size_t)(Rbase + row) * 256;
        int off = (tid & 3) * 8;
        uint4 xv[8];
        #pragma unroll
        for (int u = 0; u < 8; ++u) xv[u] = *(const uint4*)(xrow + off + u * 32);
        #pragma unroll
        for (int u = 0; u < 8; ++u) *(uint4*)&As[row][off + u * 32] = xv[u];
    }

    int oP[8], oQ[8];
    #pragma unroll
    for (int r = 0; r < 8; ++r) {
        int R = Rbase + 16 * r + ln15;
        int b = R / E_EDGES;
        int e = R - b * E_EDGES;
        int i = e / 99;
        int k = e - 99 * i;
        int j = k + (k >= i ? 1 : 0);
        oP[r] = (b * NNODE + j) * HID;
        oQ[r] = (b * NNODE + i) * HID;
    }
    __syncthreads();

    f32x4 acc[8][4];
    int wchA[4], wchB[4];
    #pragma unroll
    for (int c = 0; c < 4; ++c) {
        wchA[c] = (w * 64 + 16 * c + ln15) * wsA;
        wchB[c] = (w * 64 + 16 * c + ln15) * wsB;
    }

    // L1 GEMM: acc = x2tile @ W4a3
    #pragma unroll
    for (int r = 0; r < 8; ++r)
        #pragma unroll
        for (int c = 0; c < 4; ++c)
            acc[r][c][0] = acc[r][c][1] = acc[r][c][2] = acc[r][c][3] = 0.f;
    {
        bf16x8 wf0[4];
        #pragma unroll
        for (int c = 0; c < 4; ++c)
            wf0[c] = *(const bf16x8*)(WaT + wchA[c] + klane);
        #pragma unroll
        for (int kc = 0; kc < 8; ++kc) {
            bf16x8 wf1[4];
            if (kc < 7) {
                #pragma unroll
                for (int c = 0; c < 4; ++c)
                    wf1[c] = *(const bf16x8*)(WaT + wchA[c] + (kc + 1) * 32 + klane);
            }
            bf16x8 af[8];
            #pragma unroll
            for (int r = 0; r < 8; ++r)
                af[r] = *(const bf16x8*)&As[16 * r + ln15][kc * 32 + klane];
            #pragma unroll
            for (int r = 0; r < 8; ++r)
                #pragma unroll
                for (int c = 0; c < 4; ++c)
                    acc[r][c] = __builtin_amdgcn_mfma_f32_16x16x32_bf16(wf0[c], af[r], acc[r][c], 0, 0, 0);
            #pragma unroll
            for (int c = 0; c < 4; ++c) wf0[c] = wf1[c];
        }
    }
    __syncthreads();

    // hidden = ELU(acc + P[j] + Q[i]) -> As
    #pragma unroll
    for (int c = 0; c < 4; ++c) {
        int ch = w * 64 + 16 * c + 4 * q;
        ushort4 pv[8], qv[8];
        #pragma unroll
        for (int r = 0; r < 8; ++r) {
            pv[r] = *(const ushort4*)(Pb + oP[r] + ch);
            qv[r] = *(const ushort4*)(Qb + oQ[r] + ch);
        }
        #pragma unroll
        for (int r = 0; r < 8; ++r) {
            union { ushort4 v; ushort_t s[4]; } pu, qu;
            pu.v = pv[r]; qu.v = qv[r];
            ushort4 u;
            u.x = f2bf(elu_f(acc[r][c][0] + bf2f(pu.s[0]) + bf2f(qu.s[0])));
            u.y = f2bf(elu_f(acc[r][c][1] + bf2f(pu.s[1]) + bf2f(qu.s[1])));
            u.z = f2bf(elu_f(acc[r][c][2] + bf2f(pu.s[2]) + bf2f(qu.s[2])));
            u.w = f2bf(elu_f(acc[r][c][3] + bf2f(pu.s[3]) + bf2f(qu.s[3])));
            *(ushort4*)&As[16 * r + ln15][ch] = u;
        }
    }
    __syncthreads();

    // L2 GEMM: acc = hidden @ W4b
    #pragma unroll
    for (int r = 0; r < 8; ++r)
        #pragma unroll
        for (int c = 0; c < 4; ++c)
            acc[r][c][0] = acc[r][c][1] = acc[r][c][2] = acc[r][c][3] = 0.f;
    {
        bf16x8 wf0[4];
        #pragma unroll
        for (int c = 0; c < 4; ++c)
            wf0[c] = *(const bf16x8*)(WbT + wchB[c] + klane);
        #pragma unroll
        for (int kc = 0; kc < 8; ++kc) {
            bf16x8 wf1[4];
            if (kc < 7) {
                #pragma unroll
                for (int c = 0; c < 4; ++c)
                    wf1[c] = *(const bf16x8*)(WbT + wchB[c] + (kc + 1) * 32 + klane);
            }
            bf16x8 af[8];
            #pragma unroll
            for (int r = 0; r < 8; ++r)
                af[r] = *(const bf16x8*)&As[16 * r + ln15][kc * 32 + klane];
            #pragma unroll
            for (int r = 0; r < 8; ++r)
                #pragma unroll
                for (int c = 0; c < 4; ++c)
                    acc[r][c] = __builtin_amdgcn_mfma_f32_16x16x32_bf16(wf0[c], af[r], acc[r][c], 0, 0, 0);
            #pragma unroll
            for (int c = 0; c < 4; ++c) wf0[c] = wf1[c];
        }
    }
    __syncthreads();

    // x4 = ELU(acc + b2) -> As park
    #pragma unroll
    for (int c = 0; c < 4; ++c) {
        float4 bv = *(const float4*)&b2[w * 64 + 16 * c + 4 * q];
        #pragma unroll
        for (int r = 0; r < 8; ++r) {
            ushort4 u;
            u.x = f2bf(elu_f(acc[r][c][0] + bv.x));
            u.y = f2bf(elu_f(acc[r][c][1] + bv.y));
            u.z = f2bf(elu_f(acc[r][c][2] + bv.z));
            u.w = f2bf(elu_f(acc[r][c][3] + bv.w));
            *(ushort4*)&As[16 * r + ln15][w * 64 + 16 * c + 4 * q] = u;
        }
    }
    __syncthreads();

    #pragma unroll
    for (int m = 0; m < 16; ++m) {
        int ch = tid + m * 256;
        int row = ch >> 5;
        int o = (ch & 31) * 8;
        *(uint4*)&Y[((size_t)(Rbase + row)) * 256 + o] = *(const uint4*)&As[row][o];
    }

    if (tid < 64) {
        int c4 = tid * 4;
        float s[4] = {0.f, 0.f, 0.f, 0.f};
        float qq[4] = {0.f, 0.f, 0.f, 0.f};
        for (int r = 0; r < 128; ++r) {
            union { ushort4 v; ushort_t e[4]; } u;
            u.v = *(const ushort4*)&As[r][c4];
            #pragma unroll
            for (int g = 0; g < 4; ++g) {
                float v = bf2f(u.e[g]);
                s[g] += v;
                qq[g] = fmaf(v, v, qq[g]);
            }
        }
        size_t base = (size_t)blockIdx.x * 512;
        ushort4 us, uq;
        us.x = f2bf(s[0]);  us.y = f2bf(s[1]);  us.z = f2bf(s[2]);  us.w = f2bf(s[3]);
        uq.x = f2bf(qq[0]); uq.y = f2bf(qq[1]); uq.z = f2bf(qq[2]); uq.w = f2bf(qq[3]);
        *(ushort4*)&pstat[base + c4]       = us;
        *(ushort4*)&pstat[base + 256 + c4] = uq;
    }
}

// ---- reduce per-block partials -> stats -----------------------------------
__global__ __launch_bounds__(256)
void reduce_stats(const ushort_t* __restrict__ pstat, float* __restrict__ stats)
{
    int c = threadIdx.x;
    float s = 0.f, q = 0.f;
    for (int b = blockIdx.x; b < NBLK2; b += 64) {
        size_t base = (size_t)b * 512;
        s += bf2f(pstat[base + c]);
        q += bf2f(pstat[base + 256 + c]);
    }
    atomicAdd(&stats[c], s);
    atomicAdd(&stats[256 + c], q);
}

// ---- fold BN + fc into Wfold[256][2], bfold[2] ----------------------------
__global__ __launch_bounds__(256)
void fold_kernel(const float* __restrict__ stats,
                 const float* __restrict__ gamma, const float* __restrict__ beta,
                 const float* __restrict__ fcW, const float* __restrict__ fcb,
                 float* __restrict__ fold)
{
    __shared__ float red0[256], red1[256];
    int c = threadIdx.x;
    float mean  = stats[c] * (1.f / M_BIG);
    float var   = stats[256 + c] * (1.f / M_BIG) - mean * mean;
    float inv   = rsqrtf(var + 1e-5f);
    float scale = inv * gamma[c];
    float sh    = beta[c] - mean * scale;
    float w0 = fcW[c * 2 + 0], w1 = fcW[c * 2 + 1];
    fold[c * 2 + 0] = scale * w0;
    fold[c * 2 + 1] = scale * w1;
    red0[c] = sh * w0;
    red1[c] = sh * w1;
    __syncthreads();
    for (int off = 128; off > 0; off >>= 1) {
        if (c < off) { red0[c] += red0[c + off]; red1[c] += red1[c + off]; }
        __syncthreads();
    }
    if (c == 0) {
        fold[512] = red0[0] + fcb[0];
        fold[513] = red1[0] + fcb[1];
    }
}

// ---- final: out[R][2] = x4_row . Wfold + bfold ----------------------------
__global__ __launch_bounds__(256)
void final_kernel(const ushort_t* __restrict__ x4, const float* __restrict__ fold,
                  float* __restrict__ out)
{
    int tid  = threadIdx.x;
    int l32  = tid & 31;
    int g    = tid >> 5;
    int R = blockIdx.x * 8 + g;
    int c0 = l32 * 8;
    union { uint4 qv; ushort_t s[8]; } u;
    u.qv = *(const uint4*)(x4 + (size_t)R * 256 + c0);
    float a0 = 0.f, a1 = 0.f;
    #pragma unroll
    for (int j = 0; j < 8; ++j) {
        float v = bf2f(u.s[j]);
        a0 = fmaf(v, fold[(c0 + j) * 2 + 0], a0);
        a1 = fmaf(v, fold[(c0 + j) * 2 + 1], a1);
    }
    #pragma unroll
    for (int off = 16; off > 0; off >>= 1) {
        a0 += __shfl_down(a0, off);
        a1 += __shfl_down(a1, off);
    }
    if (l32 == 0) {
        out[(size_t)R * 2 + 0] = a0 + fold[512];
        out[(size_t)R * 2 + 1] = a1 + fold[513];
    }
}

extern "C" void kernel_launch(void* const* d_in, const int* in_sizes, int n_in,
                              void* d_out, int out_size, void* d_ws, size_t ws_size,
                              hipStream_t stream)
{
    (void)in_sizes; (void)n_in; (void)out_size; (void)ws_size;

    const float* inputs = (const float*)d_in[0];
    const float* m1W1 = (const float*)d_in[3];
    const float* m1b1 = (const float*)d_in[4];
    const float* m1W2 = (const float*)d_in[5];
    const float* m1b2 = (const float*)d_in[6];
    const float* m2W1 = (const float*)d_in[7];
    const float* m2b1 = (const float*)d_in[8];
    const float* m2W2 = (const float*)d_in[9];
    const float* m2b2 = (const float*)d_in[10];
    const float* m3W1 = (const float*)d_in[11];
    const float* m3b1 = (const float*)d_in[12];
    const float* m3W2 = (const float*)d_in[13];
    const float* m3b2 = (const float*)d_in[14];
    const float* m4W1 = (const float*)d_in[15];
    const float* m4b1 = (const float*)d_in[16];
    const float* m4W2 = (const float*)d_in[17];
    const float* m4b2 = (const float*)d_in[18];
    const float* gamma = (const float*)d_in[19];
    const float* beta  = (const float*)d_in[20];
    const float* fcW   = (const float*)d_in[21];
    const float* fcb   = (const float*)d_in[22];
    float* out = (float*)d_out;

    // ---- workspace layout (~175 MB) ----
    char* ws = (char*)d_ws;
    const size_t BIGB = (size_t)M_BIG * 256 * 2;      // 162,201,600
    const size_t HB   = (size_t)M_SMALL * 256 * 2;    // 1,638,400 bf16 small
    const size_t SM4  = (size_t)M_SMALL * 256 * 4;    // 3,276,800 fp32 small
    ushort_t* bigX     = (ushort_t*)ws;                         // x2 then x4
    ushort_t* ha       = (ushort_t*)(ws + BIGB);                // h1a / h3a
    ushort_t* hb       = (ushort_t*)(ws + BIGB + HB);           // h1  / h3
    // pstat (2475*512*2B = 2.53 MB) overlaps ha+hb: both dead at edge_mlp4
    ushort_t* pstat    = (ushort_t*)(ws + BIGB);
    float*    incoming = (float*)(ws + BIGB + 2 * HB);
    ushort_t* Pbuf     = (ushort_t*)(ws + BIGB + 2 * HB + SM4);
    ushort_t* Qbuf     = (ushort_t*)(ws + BIGB + 3 * HB + SM4);
    float*    stats    = (float*)(ws + BIGB + 4 * HB + SM4);
    float*    fold     = stats + 512;
    ushort_t* w1t      = (ushort_t*)(ws + BIGB + 4 * HB + SM4 + 8192);
    ushort_t* w1bt     = w1t  + 256 * 256;
    ushort_t* w2pt     = w1bt + 256 * 256;     // [256][512]
    ushort_t* w2t      = w2pt + 256 * 512;
    ushort_t* w3at     = w2t  + 256 * 256;
    ushort_t* w3bt     = w3at + 256 * 256;
    ushort_t* w4pt     = w3bt + 256 * 256;     // [256][768]
    ushort_t* w4bt     = w4pt + 256 * 768;

    hipMemsetAsync(stats, 0, 2048, stream);
    hipMemsetAsync(incoming, 0, SM4, stream);

    dim3 blk(256);
    wcvt_all<<<176, blk, 0, stream>>>(m1W1, m1W2, m2W1, m2W2, m3W1, m3W2, m4W1, m4W2,
                                      w1t, w1bt, w2pt, w2t, w3at, w3bt, w4pt, w4bt);
    // L1a: ELU(inputs @ m1W1 + b)  (fp32 in, K=200 padded to 224)
    small_mfma<1><<<100, blk, 0, stream>>>(inputs, nullptr, 200, 7, 1.f, 1, 100,
                                           w1t, 256, m1b1, ha,
                                           nullptr, 0, nullptr, nullptr);
    // L1b: ELU(h1a @ m1W2 + b)
    small_mfma<0><<<100, blk, 0, stream>>>(nullptr, ha, 256, 8, 1.f, 1, 100,
                                           w1bt, 256, m1b2, hb,
                                           nullptr, 0, nullptr, nullptr);
    // PQ2: P = h1@W1a + b1 ; Q = h1@W1b  (no act)
    small_mfma<0><<<200, blk, 0, stream>>>(nullptr, hb, 256, 8, 1.f, 0, 100,
                                           w2pt, 512, m2b1, Pbuf,
                                           w2pt + 256, 512, nullptr, Qbuf);
    // edge MLP2 -> x2 + e2n sums
    edge_mlp2<<<NBLK2, blk, 0, stream>>>(Pbuf, Qbuf, w2t, m2b2, bigX, incoming);
    // L3a: ELU(incoming/9900 @ m3W1 + b)  (fp32 in)
    small_mfma<1><<<100, blk, 0, stream>>>(incoming, nullptr, 256, 8, 1.f / 9900.f, 1, 100,
                                           w3at, 256, m3b1, ha,
                                           nullptr, 0, nullptr, nullptr);
    // L3b
    small_mfma<0><<<100, blk, 0, stream>>>(nullptr, ha, 256, 8, 1.f, 1, 100,
                                           w3bt, 256, m3b2, hb,
                                           nullptr, 0, nullptr, nullptr);
    // PQ4: P = h3@W4a1 + b1 ; Q = h3@W4a2
    small_mfma<0><<<200, blk, 0, stream>>>(nullptr, hb, 256, 8, 1.f, 0, 100,
                                           w4pt, 768, m4b1, Pbuf,
                                           w4pt + 256, 768, nullptr, Qbuf);
    // edge MLP4 (skip weight = w4pt cols 512.., stride 768)
    edge_mlp4<<<NBLK2, blk, 0, stream>>>(Pbuf, Qbuf, bigX,
                                         w4pt + 512, 768, w4bt, 256,
                                         m4b2, bigX, pstat);
    reduce_stats<<<64, blk, 0, stream>>>(pstat, stats);
    fold_kernel<<<1, blk, 0, stream>>>(stats, gamma, beta, fcW, fcb, fold);
    final_kernel<<<M_BIG / 8, blk, 0, stream>>>(bigX, fold, out);
}